// Round 3
// baseline (1108.350 us; speedup 1.0000x reference)
//
#include <hip/hip_runtime.h>
#include <stdint.h>

// WanAttentionBlock forward on gfx950 — round 3: m97-style GEMM
// (128x128 tile, global_load_lds 16B staging, XOR-swizzled LDS chunks).
// Shapes: B=1, S=2560, DIM=1536, HEADS=12, HD=128, FFN=8960, L2=512.

typedef unsigned short u16;
typedef __bf16 bf16x8 __attribute__((ext_vector_type(8)));
typedef float f32x4 __attribute__((ext_vector_type(4)));

#define DEV __device__ __forceinline__

DEV u16 f2b(float f) {                    // fp32 -> bf16 RNE
  uint32_t u = __float_as_uint(f);
  u += 0x7fffu + ((u >> 16) & 1u);
  return (u16)(u >> 16);
}

DEV float gelu_tanh(float v) {
  float u = 0.7978845608028654f * (v + 0.044715f * v * v * v);
  return 0.5f * v * (1.0f + tanhf(u));
}

// async 16B global->LDS (wave-uniform LDS base + lane*16)
DEV void gl_lds16(const u16* g, u16* l) {
  __builtin_amdgcn_global_load_lds(
      (const __attribute__((address_space(1))) void*)g,
      (__attribute__((address_space(3))) void*)l, 16, 0, 0);
}

// ---- block reductions (256 threads = 4 waves) ----
DEV float bred_sum(float v, float* scr) {
  #pragma unroll
  for (int o = 32; o; o >>= 1) v += __shfl_down(v, o, 64);
  if ((threadIdx.x & 63) == 0) scr[threadIdx.x >> 6] = v;
  __syncthreads();
  v = scr[0] + scr[1] + scr[2] + scr[3];
  __syncthreads();
  return v;
}
DEV float bred_max(float v, float* scr) {
  #pragma unroll
  for (int o = 32; o; o >>= 1) v = fmaxf(v, __shfl_down(v, o, 64));
  if ((threadIdx.x & 63) == 0) scr[threadIdx.x >> 6] = v;
  __syncthreads();
  v = fmaxf(fmaxf(scr[0], scr[1]), fmaxf(scr[2], scr[3]));
  __syncthreads();
  return v;
}
DEV float bred_min(float v, float* scr) {
  #pragma unroll
  for (int o = 32; o; o >>= 1) v = fminf(v, __shfl_down(v, o, 64));
  if ((threadIdx.x & 63) == 0) scr[threadIdx.x >> 6] = v;
  __syncthreads();
  v = fminf(fminf(scr[0], scr[1]), fminf(scr[2], scr[3]));
  __syncthreads();
  return v;
}

// ---- small prep kernels ----
__global__ __launch_bounds__(256) void pack_kernel(
    const float* __restrict__ e, const float* __restrict__ mod,
    const float* __restrict__ cbk, const float* __restrict__ cbv,
    float* __restrict__ em, float* __restrict__ bckv) {
  int i = blockIdx.x * 256 + threadIdx.x;
  if (i < 9216) em[i] = e[i] + mod[i];
  if (i < 3072) bckv[i] = (i < 1536) ? cbk[i] : cbv[i - 1536];
}

__global__ __launch_bounds__(256) void cvt_bf16_kernel(
    const float* __restrict__ in, u16* __restrict__ out, int n4) {
  int stride = gridDim.x * 256;
  for (int i = blockIdx.x * 256 + threadIdx.x; i < n4; i += stride) {
    float4 v = ((const float4*)in)[i];
    uint2 r;
    r.x = (uint32_t)f2b(v.x) | ((uint32_t)f2b(v.y) << 16);
    r.y = (uint32_t)f2b(v.z) | ((uint32_t)f2b(v.w) << 16);
    ((uint2*)out)[i] = r;
  }
}

// LN + modulation + per-token dynamic int8 quant (stored as exact bf16)
__global__ __launch_bounds__(256) void ln_quant_kernel(
    const float* __restrict__ x, const float* __restrict__ em,
    u16* __restrict__ qx, float* __restrict__ sx, float* __restrict__ sumq) {
  __shared__ float scr[4];
  const int row = blockIdx.x, tid = threadIdx.x;
  const float* xr = x + (size_t)row * 1536;
  float v[6], s = 0.f, s2 = 0.f;
  #pragma unroll
  for (int t = 0; t < 6; t++) { v[t] = xr[tid + t * 256]; s += v[t]; s2 += v[t] * v[t]; }
  s = bred_sum(s, scr); s2 = bred_sum(s2, scr);
  float mean = s / 1536.f;
  float var = s2 / 1536.f - mean * mean;
  float inv = rsqrtf(var + 1e-6f);
  float hv[6], amax = 0.f;
  #pragma unroll
  for (int t = 0; t < 6; t++) {
    int i = tid + t * 256;
    hv[t] = (v[t] - mean) * inv * (1.f + em[1536 + i]) + em[i];
    amax = fmaxf(amax, fabsf(hv[t]));
  }
  amax = bred_max(amax, scr);
  float sxv = fmaxf(amax / 127.f, 1e-8f);
  float qs = 0.f;
  #pragma unroll
  for (int t = 0; t < 6; t++) {
    int i = tid + t * 256;
    float q = fminf(fmaxf(rintf(hv[t] / sxv), -127.f), 127.f);
    qs += q;
    qx[(size_t)row * 1536 + i] = f2b(q);
  }
  qs = bred_sum(qs, scr);
  if (tid == 0) { sx[row] = sxv; sumq[row] = qs; }
}

// per-output-channel asymmetric int8 weight quant for stacked [wq;wk;wv]
__global__ __launch_bounds__(256) void quantw_kernel(
    const float* __restrict__ wq, const float* __restrict__ wk, const float* __restrict__ wv,
    const float* __restrict__ bq, const float* __restrict__ bk, const float* __restrict__ bv,
    u16* __restrict__ qw, float* __restrict__ sw, float* __restrict__ zp, float* __restrict__ ball) {
  __shared__ float scr[4];
  const int row = blockIdx.x, tid = threadIdx.x;
  const int sel = (row >= 3072) ? 2 : (row >= 1536 ? 1 : 0);
  const int r = row - sel * 1536;
  const float* w = sel == 0 ? wq : (sel == 1 ? wk : wv);
  const float* bb = sel == 0 ? bq : (sel == 1 ? bk : bv);
  const float* wr = w + (size_t)r * 1536;
  float v[6], mn = 1e30f, mx = -1e30f;
  #pragma unroll
  for (int t = 0; t < 6; t++) { v[t] = wr[tid + t * 256]; mn = fminf(mn, v[t]); mx = fmaxf(mx, v[t]); }
  mn = bred_min(mn, scr); mx = bred_max(mx, scr);
  float s = fmaxf((mx - mn) / 255.f, 1e-8f);
  float z = rintf(-128.f - mn / s);
  #pragma unroll
  for (int t = 0; t < 6; t++) {
    int i = tid + t * 256;
    float q = fminf(fmaxf(rintf(v[t] / s) + z, -128.f), 127.f);
    qw[(size_t)row * 1536 + i] = f2b(q);
  }
  if (tid == 0) { sw[row] = s; zp[row] = z; ball[row] = bb[r]; }
}

// ---- MFMA GEMM (m97-style): C[M,N] = A[M,K] * B[N,K]^T ----
// 128x128 tile, BK=32, async global->LDS staging, XOR chunk swizzle.
// LDS layout: tile row r (32 bf16 = 4 chunks of 16B); chunk c stored at slot
// (c + (r>>1)) & 3. Fragment reads then hit all 8 LDS 16B-columns 2-way (free).
// EP 0: +bias -> f32 | EP 1: w8a8 dequant -> f32 | EP 2: (+bias)*g + resid -> f32
// EP 3: gelu(+bias) -> bf16
template<int EP>
__global__ __launch_bounds__(256) void gemm_bt_kernel(
    const u16* __restrict__ A, const u16* __restrict__ B, void* __restrict__ Cout,
    int N, int K, const float* __restrict__ bias,
    const float* __restrict__ sxp, const float* __restrict__ sumqp,
    const float* __restrict__ swp, const float* __restrict__ zpp,
    const float* __restrict__ gp, const float* __restrict__ residp) {
  __shared__ __align__(16) u16 As[128 * 32];
  __shared__ __align__(16) u16 Bs[128 * 32];
  const int tid = threadIdx.x;
  const int wave = tid >> 6, lane = tid & 63;
  const int wm = wave >> 1, wn = wave & 1;
  const int quad = lane >> 4, l16 = lane & 15;
  const int m0 = blockIdx.y * 128, n0 = blockIdx.x * 128;

  // async-staging source coordinates (per lane, per instr i=0,1):
  // flat u16 idx e = (wave*2+i)*512 + lane*8 ; row=e>>5 ; stored-slot=lane&3
  int srow[2], scol[2];
  #pragma unroll
  for (int i = 0; i < 2; i++) {
    int row = (wave * 2 + i) * 16 + (lane >> 2);
    int chunk = ((lane & 3) - (row >> 1)) & 3;
    srow[i] = row; scol[i] = chunk * 8;
  }

  f32x4 acc[4][4];
  #pragma unroll
  for (int i = 0; i < 4; i++)
    #pragma unroll
    for (int j = 0; j < 4; j++) acc[i][j] = (f32x4){0.f, 0.f, 0.f, 0.f};

  for (int k0 = 0; k0 < K; k0 += 32) {
    #pragma unroll
    for (int i = 0; i < 2; i++) {
      gl_lds16(A + (size_t)(m0 + srow[i]) * K + k0 + scol[i], &As[(wave * 2 + i) * 512]);
      gl_lds16(B + (size_t)(n0 + srow[i]) * K + k0 + scol[i], &Bs[(wave * 2 + i) * 512]);
    }
    __syncthreads();
    bf16x8 af[4], bfv[4];
    #pragma unroll
    for (int mi = 0; mi < 4; mi++) {
      int row = wm * 64 + mi * 16 + l16;
      af[mi] = *(const bf16x8*)&As[row * 32 + (((quad + (row >> 1)) & 3) * 8)];
    }
    #pragma unroll
    for (int ni = 0; ni < 4; ni++) {
      int row = wn * 64 + ni * 16 + l16;
      bfv[ni] = *(const bf16x8*)&Bs[row * 32 + (((quad + (row >> 1)) & 3) * 8)];
    }
    #pragma unroll
    for (int mi = 0; mi < 4; mi++)
      #pragma unroll
      for (int ni = 0; ni < 4; ni++)
        acc[mi][ni] = __builtin_amdgcn_mfma_f32_16x16x32_bf16(af[mi], bfv[ni], acc[mi][ni], 0, 0, 0);
    __syncthreads();
  }
  #pragma unroll
  for (int mi = 0; mi < 4; mi++) {
    #pragma unroll
    for (int ni = 0; ni < 4; ni++) {
      int col = n0 + wn * 64 + ni * 16 + l16;
      #pragma unroll
      for (int r = 0; r < 4; r++) {
        int row = m0 + wm * 64 + mi * 16 + quad * 4 + r;
        float v = acc[mi][ni][r];
        size_t idx = (size_t)row * N + col;
        if constexpr (EP == 0) {
          ((float*)Cout)[idx] = v + bias[col];
        } else if constexpr (EP == 1) {
          v = (v - sumqp[row] * zpp[col]) * (sxp[row] * swp[col]) + bias[col];
          ((float*)Cout)[idx] = v;
        } else if constexpr (EP == 2) {
          v += bias[col];
          if (gp) v *= gp[col];
          ((float*)Cout)[idx] = v + residp[idx];
        } else {
          ((u16*)Cout)[idx] = f2b(gelu_tanh(v + bias[col]));
        }
      }
    }
  }
}

// RMS+gate+RoPE for q,k sections + plain convert for v; fp32 qkv -> bf16 qkvb.
// q section pre-scaled by 1/sqrt(128) so attention skips the softmax scale.
__global__ __launch_bounds__(256) void rmsrope_b_kernel(
    const float* __restrict__ qkv, u16* __restrict__ qkvb,
    const float* __restrict__ gq, const float* __restrict__ gk,
    const float* __restrict__ freqs, const int* __restrict__ gsz) {
  __shared__ float scr[4];
  const int row = blockIdx.x, tid = threadIdx.x;
  const float* base = qkv + (size_t)row * 4608;
  u16* ob = qkvb + (size_t)row * 4608;
  const int gh = gsz[1], gw = gsz[2];
  const int hw = gh * gw;
  const int fi = row / hw, rem = row - fi * hw;
  const int hi = rem / gw, wi = rem - hi * gw;
  #pragma unroll
  for (int part = 0; part < 2; part++) {
    const float* p = base + part * 1536;
    u16* o = ob + part * 1536;
    const float* g = part ? gk : gq;
    const float sc = part ? 1.f : 0.08838834764831845f;
    float v[6], s2 = 0.f;
    #pragma unroll
    for (int t = 0; t < 6; t++) { v[t] = p[tid + t * 256]; s2 += v[t] * v[t]; }
    s2 = bred_sum(s2, scr);
    float inv = rsqrtf(s2 / 1536.f + 1e-6f);
    #pragma unroll
    for (int t = 0; t < 3; t++) {
      int pr = tid + t * 256;               // pair index 0..767
      int c = pr & 63;
      int frow = (c < 22) ? fi : (c < 43 ? hi : wi);
      const float* fr = freqs + ((size_t)frow * 64 + c) * 2;
      float cv = fr[0], sv = fr[1];
      float x0 = p[2 * pr] * inv * g[2 * pr];
      float x1 = p[2 * pr + 1] * inv * g[2 * pr + 1];
      o[2 * pr] = f2b((x0 * cv - x1 * sv) * sc);
      o[2 * pr + 1] = f2b((x0 * sv + x1 * cv) * sc);
    }
  }
  #pragma unroll
  for (int t = 0; t < 6; t++) {
    int i = tid + t * 256;
    ob[3072 + i] = f2b(base[3072 + i]);
  }
}

// RMS (optional) + scale, fp32 -> bf16
__global__ __launch_bounds__(256) void rms_bf16_kernel(
    const float* __restrict__ X, u16* __restrict__ O, const float* __restrict__ g,
    int ldi, int ldo, float scale) {
  __shared__ float scr[4];
  const int row = blockIdx.x, tid = threadIdx.x;
  const float* xr = X + (size_t)row * ldi;
  u16* orow = O + (size_t)row * ldo;
  float v[6], s2 = 0.f;
  #pragma unroll
  for (int t = 0; t < 6; t++) { v[t] = xr[tid + t * 256]; s2 += v[t] * v[t]; }
  s2 = bred_sum(s2, scr);
  float inv = rsqrtf(s2 / 1536.f + 1e-6f) * scale;
  #pragma unroll
  for (int t = 0; t < 6; t++) {
    int i = tid + t * 256;
    orow[i] = f2b(v[t] * inv * g[i]);
  }
}

// V transpose: fp32 V[kv][ld] (per-head 128 cols) -> bf16 Vt[head][hd][Skv]
__global__ __launch_bounds__(256) void vtrans_kernel(
    const float* __restrict__ V, int ld, u16* __restrict__ Vt, int Skv) {
  __shared__ u16 T[64 * 136];
  const int h = blockIdx.y, k0 = blockIdx.x * 64, tid = threadIdx.x;
  #pragma unroll
  for (int i = 0; i < 8; i++) {
    int f4 = i * 256 + tid;              // 64 rows x 32 float4
    int row = f4 >> 5, c4 = f4 & 31;
    float4 v = *(const float4*)(V + (size_t)(k0 + row) * ld + h * 128 + c4 * 4);
    ushort4 b;
    b.x = f2b(v.x); b.y = f2b(v.y); b.z = f2b(v.z); b.w = f2b(v.w);
    *(ushort4*)&T[row * 136 + c4 * 4] = b;
  }
  __syncthreads();
  #pragma unroll
  for (int i = 0; i < 4; i++) {
    int f8 = i * 256 + tid;              // 128 hd rows x 8 chunks-of-8
    int hd = f8 >> 3, kc = f8 & 7;
    u16 tmp[8];
    #pragma unroll
    for (int j = 0; j < 8; j++) tmp[j] = T[(kc * 8 + j) * 136 + hd];
    *(uint4*)(Vt + ((size_t)h * 128 + hd) * Skv + k0 + kc * 8) = *(const uint4*)tmp;
  }
}

// ---- MFMA flash attention ----
// Q bf16 [Sq][ldq] (pre-scaled), K bf16 [Skv][ldk], Vt bf16 [12][128][kmax]
// O bf16 [Sq][ldo]. Block: 64 q-rows x 1 head; wave: 16 q-rows.
__global__ __launch_bounds__(256) void fattn_kernel(
    const u16* __restrict__ Q, int ldq, const u16* __restrict__ Kg, int ldk,
    const u16* __restrict__ Vtg, u16* __restrict__ O, int ldo,
    const int* __restrict__ klen_ptr, int kmax) {
  __shared__ __align__(16) u16 Qs[64 * 136];
  __shared__ __align__(16) u16 Ks[64 * 136];
  __shared__ __align__(16) u16 Vt[128 * 72];
  __shared__ __align__(16) u16 Pt[4][16 * 72];
  const int tid = threadIdx.x, wave = tid >> 6, lane = tid & 63;
  const int quad = lane >> 4, l16 = lane & 15;
  const int h = blockIdx.y;
  const int q0 = blockIdx.x * 64;
  int klen = klen_ptr[0]; if (klen > kmax) klen = kmax;
  const u16* vbase = Vtg + (size_t)h * 128 * kmax;

  // stage Q tile (64x128)
  #pragma unroll
  for (int i = 0; i < 4; i++) {
    int c8 = i * 256 + tid;
    int row = c8 >> 4, cc = (c8 & 15) * 8;
    *(uint4*)&Qs[row * 136 + cc] = *(const uint4*)(Q + (size_t)(q0 + row) * ldq + h * 128 + cc);
  }
  __syncthreads();
  bf16x8 qf[4];
  #pragma unroll
  for (int s = 0; s < 4; s++)
    qf[s] = *(const bf16x8*)&Qs[(wave * 16 + l16) * 136 + s * 32 + quad * 8];

  float m_r[4] = {-1e30f, -1e30f, -1e30f, -1e30f};
  float l_r[4] = {0.f, 0.f, 0.f, 0.f};
  f32x4 oacc[8];
  #pragma unroll
  for (int n8 = 0; n8 < 8; n8++) oacc[n8] = (f32x4){0.f, 0.f, 0.f, 0.f};

  const int ktiles = (klen + 63) >> 6;
  for (int kt = 0; kt < ktiles; kt++) {
    const int k0 = kt * 64;
    __syncthreads();
    // stage K tile (64x128) and V^T tile (128x64)
    #pragma unroll
    for (int i = 0; i < 4; i++) {
      int c8 = i * 256 + tid;
      int row = c8 >> 4, cc = (c8 & 15) * 8;
      *(uint4*)&Ks[row * 136 + cc] = *(const uint4*)(Kg + (size_t)(k0 + row) * ldk + h * 128 + cc);
    }
    #pragma unroll
    for (int i = 0; i < 4; i++) {
      int f8 = i * 256 + tid;
      int hd = f8 >> 3, kc = f8 & 7;
      *(uint4*)&Vt[hd * 72 + kc * 8] = *(const uint4*)(vbase + (size_t)hd * kmax + k0 + kc * 8);
    }
    __syncthreads();
    // S = Q K^T  (16 q-rows x 64 kv-cols per wave)
    f32x4 sacc[4];
    #pragma unroll
    for (int ni = 0; ni < 4; ni++) sacc[ni] = (f32x4){0.f, 0.f, 0.f, 0.f};
    #pragma unroll
    for (int ni = 0; ni < 4; ni++)
      #pragma unroll
      for (int s = 0; s < 4; s++) {
        bf16x8 kf = *(const bf16x8*)&Ks[(ni * 16 + l16) * 136 + s * 32 + quad * 8];
        sacc[ni] = __builtin_amdgcn_mfma_f32_16x16x32_bf16(qf[s], kf, sacc[ni], 0, 0, 0);
      }
    // online softmax (rows quad*4+r, replicated across l16 group)
    float alpha_r[4];
    #pragma unroll
    for (int r = 0; r < 4; r++) {
      float mx = -1e30f;
      #pragma unroll
      for (int ni = 0; ni < 4; ni++) {
        int col = k0 + ni * 16 + l16;
        float sv = (col < klen) ? sacc[ni][r] : -1e30f;
        sacc[ni][r] = sv;
        mx = fmaxf(mx, sv);
      }
      #pragma unroll
      for (int off = 1; off < 16; off <<= 1) mx = fmaxf(mx, __shfl_xor(mx, off, 64));
      float mnew = fmaxf(m_r[r], mx);
      float alpha = __expf(m_r[r] - mnew);
      float rsum = 0.f;
      float pv[4];
      #pragma unroll
      for (int ni = 0; ni < 4; ni++) {
        float p = __expf(sacc[ni][r] - mnew);
        pv[ni] = p;
        rsum += p;
      }
      #pragma unroll
      for (int off = 1; off < 16; off <<= 1) rsum += __shfl_xor(rsum, off, 64);
      l_r[r] = l_r[r] * alpha + rsum;
      m_r[r] = mnew;
      alpha_r[r] = alpha;
      #pragma unroll
      for (int ni = 0; ni < 4; ni++)
        Pt[wave][(quad * 4 + r) * 72 + ni * 16 + l16] = f2b(pv[ni]);
    }
    #pragma unroll
    for (int n8 = 0; n8 < 8; n8++)
      #pragma unroll
      for (int r = 0; r < 4; r++) oacc[n8][r] *= alpha_r[r];
    // O += P V   (P: 16x64 in A-layout via Pt; V^T tiles as B)
    #pragma unroll
    for (int s2 = 0; s2 < 2; s2++) {
      bf16x8 pf = *(const bf16x8*)&Pt[wave][l16 * 72 + s2 * 32 + quad * 8];
      #pragma unroll
      for (int n8 = 0; n8 < 8; n8++) {
        bf16x8 vf = *(const bf16x8*)&Vt[(n8 * 16 + l16) * 72 + s2 * 32 + quad * 8];
        oacc[n8] = __builtin_amdgcn_mfma_f32_16x16x32_bf16(pf, vf, oacc[n8], 0, 0, 0);
      }
    }
  }
  float rl[4];
  #pragma unroll
  for (int r = 0; r < 4; r++) rl[r] = 1.f / l_r[r];
  #pragma unroll
  for (int n8 = 0; n8 < 8; n8++)
    #pragma unroll
    for (int r = 0; r < 4; r++) {
      int row = q0 + wave * 16 + quad * 4 + r;
      O[(size_t)row * ldo + h * 128 + n8 * 16 + l16] = f2b(oacc[n8][r] * rl[r]);
    }
}

// out_bf16 = LN(x) * (addone + w) + b
__global__ __launch_bounds__(256) void ln_affine_kernel(
    const float* __restrict__ X, u16* __restrict__ O,
    const float* __restrict__ w, const float* __restrict__ b, float addone) {
  __shared__ float scr[4];
  const int row = blockIdx.x, tid = threadIdx.x;
  const float* xr = X + (size_t)row * 1536;
  float v[6], s = 0.f, s2 = 0.f;
  #pragma unroll
  for (int t = 0; t < 6; t++) { v[t] = xr[tid + t * 256]; s += v[t]; s2 += v[t] * v[t]; }
  s = bred_sum(s, scr); s2 = bred_sum(s2, scr);
  float mean = s / 1536.f;
  float inv = rsqrtf(s2 / 1536.f - mean * mean + 1e-6f);
  #pragma unroll
  for (int t = 0; t < 6; t++) {
    int i = tid + t * 256;
    O[(size_t)row * 1536 + i] = f2b((v[t] - mean) * inv * (addone + w[i]) + b[i]);
  }
}

extern "C" void kernel_launch(void* const* d_in, const int* in_sizes, int n_in,
                              void* d_out, int out_size, void* d_ws, size_t ws_size,
                              hipStream_t stream) {
  (void)in_sizes; (void)n_in; (void)out_size; (void)ws_size;
  const int S = 2560, D = 1536, L2C = 512, FF = 8960, ND = 4608, CKV = 3072;

  const float* x = (const float*)d_in[0];
  const float* e = (const float*)d_in[1];
  const int* seq_lens = (const int*)d_in[2];
  const int* grid_sz = (const int*)d_in[3];
  const float* freqs = (const float*)d_in[4];
  const float* context = (const float*)d_in[5];
  const int* ctx_lens = (const int*)d_in[6];
  const float* modulation = (const float*)d_in[7];
  const float* wq = (const float*)d_in[8];  const float* bq = (const float*)d_in[9];
  const float* wk = (const float*)d_in[10]; const float* bk = (const float*)d_in[11];
  const float* wv = (const float*)d_in[12]; const float* bv = (const float*)d_in[13];
  const float* wo = (const float*)d_in[14]; const float* bo = (const float*)d_in[15];
  const float* gq = (const float*)d_in[16]; const float* gk = (const float*)d_in[17];
  const float* n3w = (const float*)d_in[18]; const float* n3b = (const float*)d_in[19];
  const float* cwq = (const float*)d_in[20]; const float* cbq = (const float*)d_in[21];
  const float* cwk = (const float*)d_in[22]; const float* cbk = (const float*)d_in[23];
  const float* cwv = (const float*)d_in[24]; const float* cbv = (const float*)d_in[25];
  const float* cwo = (const float*)d_in[26]; const float* cbo = (const float*)d_in[27];
  const float* cgq = (const float*)d_in[28]; const float* cgk = (const float*)d_in[29];
  const float* w1 = (const float*)d_in[30]; const float* b1 = (const float*)d_in[31];
  const float* w2 = (const float*)d_in[32]; const float* b2 = (const float*)d_in[33];

  char* wsb = (char*)d_ws;
  size_t off = 0;
  auto alloc = [&](size_t bytes) -> void* {
    void* r = wsb + off;
    off += (bytes + 255) & ~(size_t)255;
    return r;
  };
  float* em   = (float*)alloc((size_t)6 * D * 4);
  float* bckv = (float*)alloc((size_t)CKV * 4);
  float* ball = (float*)alloc((size_t)ND * 4);
  float* sx   = (float*)alloc((size_t)S * 4);
  float* sumq = (float*)alloc((size_t)S * 4);
  float* sw   = (float*)alloc((size_t)ND * 4);
  float* zp   = (float*)alloc((size_t)ND * 4);
  u16* qx     = (u16*)alloc((size_t)S * D * 2);      // union: cvtg (cross V^T, 1.6MB)
  u16* qw     = (u16*)alloc((size_t)ND * D * 2);     // union: vtg (self V^T, 7.9MB)
  float* qkv  = (float*)alloc((size_t)S * ND * 4);   // union: h3 (S*FF*2 < S*ND*4)
  u16* qkvb   = (u16*)alloc((size_t)S * ND * 2);     // bf16 q(scaled)/k roped + v
  u16* attnb  = (u16*)alloc((size_t)S * D * 2);      // union: h2
  u16* hx     = (u16*)alloc((size_t)S * D * 2);      // union: cqb
  float* cq   = (float*)alloc((size_t)S * D * 4);    // union: x2
  float* ckv  = (float*)alloc((size_t)L2C * CKV * 4);
  u16* ctxb   = (u16*)alloc((size_t)L2C * D * 2);    // union: ckvb (k section bf16)
  u16* cattn  = (u16*)alloc((size_t)S * D * 2);
  u16* wo_b   = (u16*)alloc((size_t)D * D * 2);
  u16* cwq_b  = (u16*)alloc((size_t)D * D * 2);
  u16* cwkv_b = (u16*)alloc((size_t)2 * D * D * 2);
  u16* cwo_b  = (u16*)alloc((size_t)D * D * 2);
  u16* w1_b   = (u16*)alloc((size_t)FF * D * 2);
  u16* w2_b   = (u16*)alloc((size_t)D * FF * 2);
  u16* h3 = (u16*)qkv;
  u16* h2 = attnb;
  u16* vtg = qw;        // [12][128][2560] bf16
  u16* cvtg = qx;       // [12][128][512] bf16
  u16* cqb = hx;
  u16* ckvb = ctxb;
  float* x2 = cq;
  float* x1 = (float*)d_out;
  float* outp = (float*)d_out;

  auto cvt = [&](const float* in, u16* op, size_t n) {
    int n4 = (int)(n / 4);
    int blocks = (n4 + 255) / 256; if (blocks > 4096) blocks = 4096;
    cvt_bf16_kernel<<<blocks, 256, 0, stream>>>(in, op, n4);
  };

  pack_kernel<<<36, 256, 0, stream>>>(e, modulation, cbk, cbv, em, bckv);
  cvt(wo, wo_b, (size_t)D * D);
  cvt(cwq, cwq_b, (size_t)D * D);
  cvt(cwk, cwkv_b, (size_t)D * D);
  cvt(cwv, cwkv_b + (size_t)D * D, (size_t)D * D);
  cvt(cwo, cwo_b, (size_t)D * D);
  cvt(w1, w1_b, (size_t)FF * D);
  cvt(w2, w2_b, (size_t)D * FF);
  cvt(context, ctxb, (size_t)L2C * D);

  ln_quant_kernel<<<S, 256, 0, stream>>>(x, em, qx, sx, sumq);
  quantw_kernel<<<ND, 256, 0, stream>>>(wq, wk, wv, bq, bk, bv, qw, sw, zp, ball);

  // qkv = dequant(qx @ qw^T) : [S][4608] fp32
  gemm_bt_kernel<1><<<dim3(ND / 128, S / 128), 256, 0, stream>>>(
      qx, qw, qkv, ND, D, ball, sx, sumq, sw, zp, nullptr, nullptr);

  // qkvb = bf16(rms+rope(q,k), v); q pre-scaled by 1/sqrt(128)
  rmsrope_b_kernel<<<S, 256, 0, stream>>>(qkv, qkvb, gq, gk, freqs, grid_sz);
  // vtg = V^T (self)  [12][128][2560]
  vtrans_kernel<<<dim3(S / 64, 12), 256, 0, stream>>>(qkv + 3072, ND, vtg, S);

  fattn_kernel<<<dim3(S / 64, 12), 256, 0, stream>>>(
      qkvb, ND, qkvb + 1536, ND, vtg, attnb, D, seq_lens, S);

  // x1 = x + (attn @ wo^T + bo) * gm
  gemm_bt_kernel<2><<<dim3(D / 128, S / 128), 256, 0, stream>>>(
      attnb, wo_b, x1, D, D, bo, nullptr, nullptr, nullptr, nullptr, em + 2 * D, x);

  ln_affine_kernel<<<S, 256, 0, stream>>>(x1, hx, n3w, n3b, 0.f);

  gemm_bt_kernel<0><<<dim3(D / 128, S / 128), 256, 0, stream>>>(
      hx, cwq_b, cq, D, D, cbq, nullptr, nullptr, nullptr, nullptr, nullptr, nullptr);
  gemm_bt_kernel<0><<<dim3(CKV / 128, L2C / 128), 256, 0, stream>>>(
      ctxb, cwkv_b, ckv, CKV, D, bckv, nullptr, nullptr, nullptr, nullptr, nullptr, nullptr);

  // cqb = bf16(rms(cq)*cgq * 1/sqrt(128)); ckvb = bf16(rms(ck)*cgk)
  rms_bf16_kernel<<<S, 256, 0, stream>>>(cq, cqb, cgq, D, D, 0.08838834764831845f);
  rms_bf16_kernel<<<L2C, 256, 0, stream>>>(ckv, ckvb, cgk, CKV, D, 1.f);
  // cvtg = V^T (cross) [12][128][512]
  vtrans_kernel<<<dim3(L2C / 64, 12), 256, 0, stream>>>(ckv + 1536, CKV, cvtg, L2C);

  fattn_kernel<<<dim3(S / 64, 12), 256, 0, stream>>>(
      cqb, D, ckvb, D, cvtg, cattn, D, ctx_lens, L2C);

  // x2 = x1 + cattn @ cwo^T + cbo
  gemm_bt_kernel<2><<<dim3(D / 128, S / 128), 256, 0, stream>>>(
      cattn, cwo_b, x2, D, D, cbo, nullptr, nullptr, nullptr, nullptr, nullptr, x1);

  ln_affine_kernel<<<S, 256, 0, stream>>>(x2, h2, em + 4 * D, em + 3 * D, 1.f);

  // h3 = gelu(h2 @ w1^T + b1) (bf16)
  gemm_bt_kernel<3><<<dim3(FF / 128, S / 128), 256, 0, stream>>>(
      h2, w1_b, h3, FF, D, b1, nullptr, nullptr, nullptr, nullptr, nullptr, nullptr);

  // out = x2 + (h3 @ w2^T + b2) * gmlp
  gemm_bt_kernel<2><<<dim3(D / 128, S / 128), 256, 0, stream>>>(
      h3, w2_b, outp, D, FF, b2, nullptr, nullptr, nullptr, nullptr, em + 5 * D, x2);
}

// Round 4
// 1012.508 us; speedup vs baseline: 1.0947x; 1.0947x over previous
//
#include <hip/hip_runtime.h>
#include <stdint.h>

// WanAttentionBlock forward on gfx950 — round 4.
// GEMMs: 128x128 m97-style for big-N (qkv, w1); 64x128 double-buffered
// single-barrier variant for N=1536 GEMMs (occupancy fix, 240->480 blocks).
// Shapes: B=1, S=2560, DIM=1536, HEADS=12, HD=128, FFN=8960, L2=512.

typedef unsigned short u16;
typedef __bf16 bf16x8 __attribute__((ext_vector_type(8)));
typedef float f32x4 __attribute__((ext_vector_type(4)));

#define DEV __device__ __forceinline__

DEV u16 f2b(float f) {                    // fp32 -> bf16 RNE
  uint32_t u = __float_as_uint(f);
  u += 0x7fffu + ((u >> 16) & 1u);
  return (u16)(u >> 16);
}

DEV float gelu_tanh(float v) {
  float u = 0.7978845608028654f * (v + 0.044715f * v * v * v);
  return 0.5f * v * (1.0f + tanhf(u));
}

// async 16B global->LDS (wave-uniform LDS base + lane*16)
DEV void gl_lds16(const u16* g, u16* l) {
  __builtin_amdgcn_global_load_lds(
      (const __attribute__((address_space(1))) void*)g,
      (__attribute__((address_space(3))) void*)l, 16, 0, 0);
}

// ---- block reductions (256 threads = 4 waves) ----
DEV float bred_sum(float v, float* scr) {
  #pragma unroll
  for (int o = 32; o; o >>= 1) v += __shfl_down(v, o, 64);
  if ((threadIdx.x & 63) == 0) scr[threadIdx.x >> 6] = v;
  __syncthreads();
  v = scr[0] + scr[1] + scr[2] + scr[3];
  __syncthreads();
  return v;
}
DEV float bred_max(float v, float* scr) {
  #pragma unroll
  for (int o = 32; o; o >>= 1) v = fmaxf(v, __shfl_down(v, o, 64));
  if ((threadIdx.x & 63) == 0) scr[threadIdx.x >> 6] = v;
  __syncthreads();
  v = fmaxf(fmaxf(scr[0], scr[1]), fmaxf(scr[2], scr[3]));
  __syncthreads();
  return v;
}
DEV float bred_min(float v, float* scr) {
  #pragma unroll
  for (int o = 32; o; o >>= 1) v = fminf(v, __shfl_down(v, o, 64));
  if ((threadIdx.x & 63) == 0) scr[threadIdx.x >> 6] = v;
  __syncthreads();
  v = fminf(fminf(scr[0], scr[1]), fminf(scr[2], scr[3]));
  __syncthreads();
  return v;
}

// ---- small prep kernels ----
__global__ __launch_bounds__(256) void pack_kernel(
    const float* __restrict__ e, const float* __restrict__ mod,
    const float* __restrict__ cbk, const float* __restrict__ cbv,
    float* __restrict__ em, float* __restrict__ bckv) {
  int i = blockIdx.x * 256 + threadIdx.x;
  if (i < 9216) em[i] = e[i] + mod[i];
  if (i < 3072) bckv[i] = (i < 1536) ? cbk[i] : cbv[i - 1536];
}

__global__ __launch_bounds__(256) void cvt_bf16_kernel(
    const float* __restrict__ in, u16* __restrict__ out, int n4) {
  int stride = gridDim.x * 256;
  for (int i = blockIdx.x * 256 + threadIdx.x; i < n4; i += stride) {
    float4 v = ((const float4*)in)[i];
    uint2 r;
    r.x = (uint32_t)f2b(v.x) | ((uint32_t)f2b(v.y) << 16);
    r.y = (uint32_t)f2b(v.z) | ((uint32_t)f2b(v.w) << 16);
    ((uint2*)out)[i] = r;
  }
}

// LN + modulation + per-token dynamic int8 quant (stored as exact bf16)
__global__ __launch_bounds__(256) void ln_quant_kernel(
    const float* __restrict__ x, const float* __restrict__ em,
    u16* __restrict__ qx, float* __restrict__ sx, float* __restrict__ sumq) {
  __shared__ float scr[4];
  const int row = blockIdx.x, tid = threadIdx.x;
  const float* xr = x + (size_t)row * 1536;
  float v[6], s = 0.f, s2 = 0.f;
  #pragma unroll
  for (int t = 0; t < 6; t++) { v[t] = xr[tid + t * 256]; s += v[t]; s2 += v[t] * v[t]; }
  s = bred_sum(s, scr); s2 = bred_sum(s2, scr);
  float mean = s / 1536.f;
  float var = s2 / 1536.f - mean * mean;
  float inv = rsqrtf(var + 1e-6f);
  float hv[6], amax = 0.f;
  #pragma unroll
  for (int t = 0; t < 6; t++) {
    int i = tid + t * 256;
    hv[t] = (v[t] - mean) * inv * (1.f + em[1536 + i]) + em[i];
    amax = fmaxf(amax, fabsf(hv[t]));
  }
  amax = bred_max(amax, scr);
  float sxv = fmaxf(amax / 127.f, 1e-8f);
  float qs = 0.f;
  #pragma unroll
  for (int t = 0; t < 6; t++) {
    int i = tid + t * 256;
    float q = fminf(fmaxf(rintf(hv[t] / sxv), -127.f), 127.f);
    qs += q;
    qx[(size_t)row * 1536 + i] = f2b(q);
  }
  qs = bred_sum(qs, scr);
  if (tid == 0) { sx[row] = sxv; sumq[row] = qs; }
}

// per-output-channel asymmetric int8 weight quant for stacked [wq;wk;wv]
__global__ __launch_bounds__(256) void quantw_kernel(
    const float* __restrict__ wq, const float* __restrict__ wk, const float* __restrict__ wv,
    const float* __restrict__ bq, const float* __restrict__ bk, const float* __restrict__ bv,
    u16* __restrict__ qw, float* __restrict__ sw, float* __restrict__ zp, float* __restrict__ ball) {
  __shared__ float scr[4];
  const int row = blockIdx.x, tid = threadIdx.x;
  const int sel = (row >= 3072) ? 2 : (row >= 1536 ? 1 : 0);
  const int r = row - sel * 1536;
  const float* w = sel == 0 ? wq : (sel == 1 ? wk : wv);
  const float* bb = sel == 0 ? bq : (sel == 1 ? bk : bv);
  const float* wr = w + (size_t)r * 1536;
  float v[6], mn = 1e30f, mx = -1e30f;
  #pragma unroll
  for (int t = 0; t < 6; t++) { v[t] = wr[tid + t * 256]; mn = fminf(mn, v[t]); mx = fmaxf(mx, v[t]); }
  mn = bred_min(mn, scr); mx = bred_max(mx, scr);
  float s = fmaxf((mx - mn) / 255.f, 1e-8f);
  float z = rintf(-128.f - mn / s);
  #pragma unroll
  for (int t = 0; t < 6; t++) {
    int i = tid + t * 256;
    float q = fminf(fmaxf(rintf(v[t] / s) + z, -128.f), 127.f);
    qw[(size_t)row * 1536 + i] = f2b(q);
  }
  if (tid == 0) { sw[row] = s; zp[row] = z; ball[row] = bb[r]; }
}

// epilogue helper
template<int EP>
DEV void gemm_epilogue(float v, int row, int col, int N, void* Cout,
                       const float* bias, const float* sxp, const float* sumqp,
                       const float* swp, const float* zpp,
                       const float* gp, const float* residp) {
  size_t idx = (size_t)row * N + col;
  if constexpr (EP == 0) {
    ((float*)Cout)[idx] = v + bias[col];
  } else if constexpr (EP == 1) {
    v = (v - sumqp[row] * zpp[col]) * (sxp[row] * swp[col]) + bias[col];
    ((float*)Cout)[idx] = v;
  } else if constexpr (EP == 2) {
    v += bias[col];
    if (gp) v *= gp[col];
    ((float*)Cout)[idx] = v + residp[idx];
  } else {
    ((u16*)Cout)[idx] = f2b(gelu_tanh(v + bias[col]));
  }
}

// ---- MFMA GEMM (m97-style): C[M,N] = A[M,K] * B[N,K]^T ----
// 128x128 tile, BK=32, async global->LDS staging, XOR chunk swizzle.
// For large-N GEMMs (>=720 blocks). EP as in gemm_epilogue.
template<int EP>
__global__ __launch_bounds__(256) void gemm_bt_kernel(
    const u16* __restrict__ A, const u16* __restrict__ B, void* __restrict__ Cout,
    int N, int K, const float* __restrict__ bias,
    const float* __restrict__ sxp, const float* __restrict__ sumqp,
    const float* __restrict__ swp, const float* __restrict__ zpp,
    const float* __restrict__ gp, const float* __restrict__ residp) {
  __shared__ __align__(16) u16 As[128 * 32];
  __shared__ __align__(16) u16 Bs[128 * 32];
  const int tid = threadIdx.x;
  const int wave = tid >> 6, lane = tid & 63;
  const int wm = wave >> 1, wn = wave & 1;
  const int quad = lane >> 4, l16 = lane & 15;
  const int m0 = blockIdx.y * 128, n0 = blockIdx.x * 128;

  int srow[2], scol[2];
  #pragma unroll
  for (int i = 0; i < 2; i++) {
    int row = (wave * 2 + i) * 16 + (lane >> 2);
    int chunk = ((lane & 3) - (row >> 1)) & 3;
    srow[i] = row; scol[i] = chunk * 8;
  }

  f32x4 acc[4][4];
  #pragma unroll
  for (int i = 0; i < 4; i++)
    #pragma unroll
    for (int j = 0; j < 4; j++) acc[i][j] = (f32x4){0.f, 0.f, 0.f, 0.f};

  for (int k0 = 0; k0 < K; k0 += 32) {
    #pragma unroll
    for (int i = 0; i < 2; i++) {
      gl_lds16(A + (size_t)(m0 + srow[i]) * K + k0 + scol[i], &As[(wave * 2 + i) * 512]);
      gl_lds16(B + (size_t)(n0 + srow[i]) * K + k0 + scol[i], &Bs[(wave * 2 + i) * 512]);
    }
    __syncthreads();
    bf16x8 af[4], bfv[4];
    #pragma unroll
    for (int mi = 0; mi < 4; mi++) {
      int row = wm * 64 + mi * 16 + l16;
      af[mi] = *(const bf16x8*)&As[row * 32 + (((quad + (row >> 1)) & 3) * 8)];
    }
    #pragma unroll
    for (int ni = 0; ni < 4; ni++) {
      int row = wn * 64 + ni * 16 + l16;
      bfv[ni] = *(const bf16x8*)&Bs[row * 32 + (((quad + (row >> 1)) & 3) * 8)];
    }
    #pragma unroll
    for (int mi = 0; mi < 4; mi++)
      #pragma unroll
      for (int ni = 0; ni < 4; ni++)
        acc[mi][ni] = __builtin_amdgcn_mfma_f32_16x16x32_bf16(af[mi], bfv[ni], acc[mi][ni], 0, 0, 0);
    __syncthreads();
  }
  #pragma unroll
  for (int mi = 0; mi < 4; mi++)
    #pragma unroll
    for (int ni = 0; ni < 4; ni++) {
      int col = n0 + wn * 64 + ni * 16 + l16;
      #pragma unroll
      for (int r = 0; r < 4; r++)
        gemm_epilogue<EP>(acc[mi][ni][r], m0 + wm * 64 + mi * 16 + quad * 4 + r, col,
                          N, Cout, bias, sxp, sumqp, swp, zpp, gp, residp);
    }
}

// ---- 64x128 double-buffered GEMM for N=1536 outputs (occupancy fix) ----
// One barrier per k-step: sync drains buf_cur loads AND releases buf_prev;
// next-step loads issue right after, overlapping with compute.
template<int EP>
__global__ __launch_bounds__(256) void gemm64_bt_kernel(
    const u16* __restrict__ A, const u16* __restrict__ B, void* __restrict__ Cout,
    int N, int K, const float* __restrict__ bias,
    const float* __restrict__ sxp, const float* __restrict__ sumqp,
    const float* __restrict__ swp, const float* __restrict__ zpp,
    const float* __restrict__ gp, const float* __restrict__ residp) {
  __shared__ __align__(16) u16 As[2][64 * 32];
  __shared__ __align__(16) u16 Bs[2][128 * 32];
  const int tid = threadIdx.x;
  const int wave = tid >> 6, lane = tid & 63;
  const int quad = lane >> 4, l16 = lane & 15;
  const int m0 = blockIdx.y * 64, n0 = blockIdx.x * 128;

  const int arow = wave * 16 + (lane >> 2);
  const int acol = (((lane & 3) - (arow >> 1)) & 3) * 8;
  int brow[2], bcol[2];
  #pragma unroll
  for (int i = 0; i < 2; i++) {
    int row = (wave * 2 + i) * 16 + (lane >> 2);
    brow[i] = row; bcol[i] = (((lane & 3) - (row >> 1)) & 3) * 8;
  }

  f32x4 acc[8];
  #pragma unroll
  for (int i = 0; i < 8; i++) acc[i] = (f32x4){0.f, 0.f, 0.f, 0.f};

  const int nk = K >> 5;
  // stage k-step 0 into buf 0
  gl_lds16(A + (size_t)(m0 + arow) * K + acol, &As[0][wave * 512]);
  #pragma unroll
  for (int i = 0; i < 2; i++)
    gl_lds16(B + (size_t)(n0 + brow[i]) * K + bcol[i], &Bs[0][(wave * 2 + i) * 512]);

  for (int kt = 0; kt < nk; kt++) {
    __syncthreads();                 // drains buf_cur loads; releases buf_next for overwrite
    const int cur = kt & 1;
    if (kt + 1 < nk) {
      const int k0n = (kt + 1) << 5;
      gl_lds16(A + (size_t)(m0 + arow) * K + k0n + acol, &As[1 - cur][wave * 512]);
      #pragma unroll
      for (int i = 0; i < 2; i++)
        gl_lds16(B + (size_t)(n0 + brow[i]) * K + k0n + bcol[i], &Bs[1 - cur][(wave * 2 + i) * 512]);
    }
    const int ar = wave * 16 + l16;
    bf16x8 af = *(const bf16x8*)&As[cur][ar * 32 + (((quad + (ar >> 1)) & 3) * 8)];
    #pragma unroll
    for (int ni = 0; ni < 8; ni++) {
      int row = ni * 16 + l16;
      bf16x8 bf = *(const bf16x8*)&Bs[cur][row * 32 + (((quad + (row >> 1)) & 3) * 8)];
      acc[ni] = __builtin_amdgcn_mfma_f32_16x16x32_bf16(af, bf, acc[ni], 0, 0, 0);
    }
  }
  #pragma unroll
  for (int ni = 0; ni < 8; ni++) {
    int col = n0 + ni * 16 + l16;
    #pragma unroll
    for (int r = 0; r < 4; r++)
      gemm_epilogue<EP>(acc[ni][r], m0 + wave * 16 + quad * 4 + r, col,
                        N, Cout, bias, sxp, sumqp, swp, zpp, gp, residp);
  }
}

// RMS+gate+RoPE for q,k sections + plain convert for v; fp32 qkv -> bf16 qkvb.
// q section pre-scaled by 1/sqrt(128) so attention skips the softmax scale.
__global__ __launch_bounds__(256) void rmsrope_b_kernel(
    const float* __restrict__ qkv, u16* __restrict__ qkvb,
    const float* __restrict__ gq, const float* __restrict__ gk,
    const float* __restrict__ freqs, const int* __restrict__ gsz) {
  __shared__ float scr[4];
  const int row = blockIdx.x, tid = threadIdx.x;
  const float* base = qkv + (size_t)row * 4608;
  u16* ob = qkvb + (size_t)row * 4608;
  const int gh = gsz[1], gw = gsz[2];
  const int hw = gh * gw;
  const int fi = row / hw, rem = row - fi * hw;
  const int hi = rem / gw, wi = rem - hi * gw;
  #pragma unroll
  for (int part = 0; part < 2; part++) {
    const float* p = base + part * 1536;
    u16* o = ob + part * 1536;
    const float* g = part ? gk : gq;
    const float sc = part ? 1.f : 0.08838834764831845f;
    float v[6], s2 = 0.f;
    #pragma unroll
    for (int t = 0; t < 6; t++) { v[t] = p[tid + t * 256]; s2 += v[t] * v[t]; }
    s2 = bred_sum(s2, scr);
    float inv = rsqrtf(s2 / 1536.f + 1e-6f);
    #pragma unroll
    for (int t = 0; t < 3; t++) {
      int pr = tid + t * 256;               // pair index 0..767
      int c = pr & 63;
      int frow = (c < 22) ? fi : (c < 43 ? hi : wi);
      const float* fr = freqs + ((size_t)frow * 64 + c) * 2;
      float cv = fr[0], sv = fr[1];
      float x0 = p[2 * pr] * inv * g[2 * pr];
      float x1 = p[2 * pr + 1] * inv * g[2 * pr + 1];
      o[2 * pr] = f2b((x0 * cv - x1 * sv) * sc);
      o[2 * pr + 1] = f2b((x0 * sv + x1 * cv) * sc);
    }
  }
  #pragma unroll
  for (int t = 0; t < 6; t++) {
    int i = tid + t * 256;
    ob[3072 + i] = f2b(base[3072 + i]);
  }
}

// RMS (optional) + scale, fp32 -> bf16
__global__ __launch_bounds__(256) void rms_bf16_kernel(
    const float* __restrict__ X, u16* __restrict__ O, const float* __restrict__ g,
    int ldi, int ldo, float scale) {
  __shared__ float scr[4];
  const int row = blockIdx.x, tid = threadIdx.x;
  const float* xr = X + (size_t)row * ldi;
  u16* orow = O + (size_t)row * ldo;
  float v[6], s2 = 0.f;
  #pragma unroll
  for (int t = 0; t < 6; t++) { v[t] = xr[tid + t * 256]; s2 += v[t] * v[t]; }
  s2 = bred_sum(s2, scr);
  float inv = rsqrtf(s2 / 1536.f + 1e-6f) * scale;
  #pragma unroll
  for (int t = 0; t < 6; t++) {
    int i = tid + t * 256;
    orow[i] = f2b(v[t] * inv * g[i]);
  }
}

// V transpose: fp32 V[kv][ld] (per-head 128 cols) -> bf16 Vt[head][hd][Skv]
__global__ __launch_bounds__(256) void vtrans_kernel(
    const float* __restrict__ V, int ld, u16* __restrict__ Vt, int Skv) {
  __shared__ u16 T[64 * 136];
  const int h = blockIdx.y, k0 = blockIdx.x * 64, tid = threadIdx.x;
  #pragma unroll
  for (int i = 0; i < 8; i++) {
    int f4 = i * 256 + tid;              // 64 rows x 32 float4
    int row = f4 >> 5, c4 = f4 & 31;
    float4 v = *(const float4*)(V + (size_t)(k0 + row) * ld + h * 128 + c4 * 4);
    ushort4 b;
    b.x = f2b(v.x); b.y = f2b(v.y); b.z = f2b(v.z); b.w = f2b(v.w);
    *(ushort4*)&T[row * 136 + c4 * 4] = b;
  }
  __syncthreads();
  #pragma unroll
  for (int i = 0; i < 4; i++) {
    int f8 = i * 256 + tid;              // 128 hd rows x 8 chunks-of-8
    int hd = f8 >> 3, kc = f8 & 7;
    u16 tmp[8];
    #pragma unroll
    for (int j = 0; j < 8; j++) tmp[j] = T[(kc * 8 + j) * 136 + hd];
    *(uint4*)(Vt + ((size_t)h * 128 + hd) * Skv + k0 + kc * 8) = *(const uint4*)tmp;
  }
}

// ---- MFMA flash attention ----
// Q bf16 [Sq][ldq] (pre-scaled), K bf16 [Skv][ldk], Vt bf16 [12][128][kmax]
// O bf16 [Sq][ldo]. Block: 64 q-rows x 1 head; wave: 16 q-rows.
__global__ __launch_bounds__(256) void fattn_kernel(
    const u16* __restrict__ Q, int ldq, const u16* __restrict__ Kg, int ldk,
    const u16* __restrict__ Vtg, u16* __restrict__ O, int ldo,
    const int* __restrict__ klen_ptr, int kmax) {
  __shared__ __align__(16) u16 Qs[64 * 136];
  __shared__ __align__(16) u16 Ks[64 * 136];
  __shared__ __align__(16) u16 Vt[128 * 72];
  __shared__ __align__(16) u16 Pt[4][16 * 72];
  const int tid = threadIdx.x, wave = tid >> 6, lane = tid & 63;
  const int quad = lane >> 4, l16 = lane & 15;
  const int h = blockIdx.y;
  const int q0 = blockIdx.x * 64;
  int klen = klen_ptr[0]; if (klen > kmax) klen = kmax;
  const u16* vbase = Vtg + (size_t)h * 128 * kmax;

  // stage Q tile (64x128)
  #pragma unroll
  for (int i = 0; i < 4; i++) {
    int c8 = i * 256 + tid;
    int row = c8 >> 4, cc = (c8 & 15) * 8;
    *(uint4*)&Qs[row * 136 + cc] = *(const uint4*)(Q + (size_t)(q0 + row) * ldq + h * 128 + cc);
  }
  __syncthreads();
  bf16x8 qf[4];
  #pragma unroll
  for (int s = 0; s < 4; s++)
    qf[s] = *(const bf16x8*)&Qs[(wave * 16 + l16) * 136 + s * 32 + quad * 8];

  float m_r[4] = {-1e30f, -1e30f, -1e30f, -1e30f};
  float l_r[4] = {0.f, 0.f, 0.f, 0.f};
  f32x4 oacc[8];
  #pragma unroll
  for (int n8 = 0; n8 < 8; n8++) oacc[n8] = (f32x4){0.f, 0.f, 0.f, 0.f};

  const int ktiles = (klen + 63) >> 6;
  for (int kt = 0; kt < ktiles; kt++) {
    const int k0 = kt * 64;
    __syncthreads();
    // stage K tile (64x128) and V^T tile (128x64)
    #pragma unroll
    for (int i = 0; i < 4; i++) {
      int c8 = i * 256 + tid;
      int row = c8 >> 4, cc = (c8 & 15) * 8;
      *(uint4*)&Ks[row * 136 + cc] = *(const uint4*)(Kg + (size_t)(k0 + row) * ldk + h * 128 + cc);
    }
    #pragma unroll
    for (int i = 0; i < 4; i++) {
      int f8 = i * 256 + tid;
      int hd = f8 >> 3, kc = f8 & 7;
      *(uint4*)&Vt[hd * 72 + kc * 8] = *(const uint4*)(vbase + (size_t)hd * kmax + k0 + kc * 8);
    }
    __syncthreads();
    // S = Q K^T  (16 q-rows x 64 kv-cols per wave)
    f32x4 sacc[4];
    #pragma unroll
    for (int ni = 0; ni < 4; ni++) sacc[ni] = (f32x4){0.f, 0.f, 0.f, 0.f};
    #pragma unroll
    for (int ni = 0; ni < 4; ni++)
      #pragma unroll
      for (int s = 0; s < 4; s++) {
        bf16x8 kf = *(const bf16x8*)&Ks[(ni * 16 + l16) * 136 + s * 32 + quad * 8];
        sacc[ni] = __builtin_amdgcn_mfma_f32_16x16x32_bf16(qf[s], kf, sacc[ni], 0, 0, 0);
      }
    // online softmax (rows quad*4+r, replicated across l16 group)
    float alpha_r[4];
    #pragma unroll
    for (int r = 0; r < 4; r++) {
      float mx = -1e30f;
      #pragma unroll
      for (int ni = 0; ni < 4; ni++) {
        int col = k0 + ni * 16 + l16;
        float sv = (col < klen) ? sacc[ni][r] : -1e30f;
        sacc[ni][r] = sv;
        mx = fmaxf(mx, sv);
      }
      #pragma unroll
      for (int off = 1; off < 16; off <<= 1) mx = fmaxf(mx, __shfl_xor(mx, off, 64));
      float mnew = fmaxf(m_r[r], mx);
      float alpha = __expf(m_r[r] - mnew);
      float rsum = 0.f;
      float pv[4];
      #pragma unroll
      for (int ni = 0; ni < 4; ni++) {
        float p = __expf(sacc[ni][r] - mnew);
        pv[ni] = p;
        rsum += p;
      }
      #pragma unroll
      for (int off = 1; off < 16; off <<= 1) rsum += __shfl_xor(rsum, off, 64);
      l_r[r] = l_r[r] * alpha + rsum;
      m_r[r] = mnew;
      alpha_r[r] = alpha;
      #pragma unroll
      for (int ni = 0; ni < 4; ni++)
        Pt[wave][(quad * 4 + r) * 72 + ni * 16 + l16] = f2b(pv[ni]);
    }
    #pragma unroll
    for (int n8 = 0; n8 < 8; n8++)
      #pragma unroll
      for (int r = 0; r < 4; r++) oacc[n8][r] *= alpha_r[r];
    // O += P V   (P: 16x64 in A-layout via Pt; V^T tiles as B)
    #pragma unroll
    for (int s2 = 0; s2 < 2; s2++) {
      bf16x8 pf = *(const bf16x8*)&Pt[wave][l16 * 72 + s2 * 32 + quad * 8];
      #pragma unroll
      for (int n8 = 0; n8 < 8; n8++) {
        bf16x8 vf = *(const bf16x8*)&Vt[(n8 * 16 + l16) * 72 + s2 * 32 + quad * 8];
        oacc[n8] = __builtin_amdgcn_mfma_f32_16x16x32_bf16(pf, vf, oacc[n8], 0, 0, 0);
      }
    }
  }
  float rl[4];
  #pragma unroll
  for (int r = 0; r < 4; r++) rl[r] = 1.f / l_r[r];
  #pragma unroll
  for (int n8 = 0; n8 < 8; n8++)
    #pragma unroll
    for (int r = 0; r < 4; r++) {
      int row = q0 + wave * 16 + quad * 4 + r;
      O[(size_t)row * ldo + h * 128 + n8 * 16 + l16] = f2b(oacc[n8][r] * rl[r]);
    }
}

// out_bf16 = LN(x) * (addone + w) + b
__global__ __launch_bounds__(256) void ln_affine_kernel(
    const float* __restrict__ X, u16* __restrict__ O,
    const float* __restrict__ w, const float* __restrict__ b, float addone) {
  __shared__ float scr[4];
  const int row = blockIdx.x, tid = threadIdx.x;
  const float* xr = X + (size_t)row * 1536;
  float v[6], s = 0.f, s2 = 0.f;
  #pragma unroll
  for (int t = 0; t < 6; t++) { v[t] = xr[tid + t * 256]; s += v[t]; s2 += v[t] * v[t]; }
  s = bred_sum(s, scr); s2 = bred_sum(s2, scr);
  float mean = s / 1536.f;
  float inv = rsqrtf(s2 / 1536.f - mean * mean + 1e-6f);
  #pragma unroll
  for (int t = 0; t < 6; t++) {
    int i = tid + t * 256;
    O[(size_t)row * 1536 + i] = f2b((v[t] - mean) * inv * (addone + w[i]) + b[i]);
  }
}

extern "C" void kernel_launch(void* const* d_in, const int* in_sizes, int n_in,
                              void* d_out, int out_size, void* d_ws, size_t ws_size,
                              hipStream_t stream) {
  (void)in_sizes; (void)n_in; (void)out_size; (void)ws_size;
  const int S = 2560, D = 1536, L2C = 512, FF = 8960, ND = 4608, CKV = 3072;

  const float* x = (const float*)d_in[0];
  const float* e = (const float*)d_in[1];
  const int* seq_lens = (const int*)d_in[2];
  const int* grid_sz = (const int*)d_in[3];
  const float* freqs = (const float*)d_in[4];
  const float* context = (const float*)d_in[5];
  const int* ctx_lens = (const int*)d_in[6];
  const float* modulation = (const float*)d_in[7];
  const float* wq = (const float*)d_in[8];  const float* bq = (const float*)d_in[9];
  const float* wk = (const float*)d_in[10]; const float* bk = (const float*)d_in[11];
  const float* wv = (const float*)d_in[12]; const float* bv = (const float*)d_in[13];
  const float* wo = (const float*)d_in[14]; const float* bo = (const float*)d_in[15];
  const float* gq = (const float*)d_in[16]; const float* gk = (const float*)d_in[17];
  const float* n3w = (const float*)d_in[18]; const float* n3b = (const float*)d_in[19];
  const float* cwq = (const float*)d_in[20]; const float* cbq = (const float*)d_in[21];
  const float* cwk = (const float*)d_in[22]; const float* cbk = (const float*)d_in[23];
  const float* cwv = (const float*)d_in[24]; const float* cbv = (const float*)d_in[25];
  const float* cwo = (const float*)d_in[26]; const float* cbo = (const float*)d_in[27];
  const float* cgq = (const float*)d_in[28]; const float* cgk = (const float*)d_in[29];
  const float* w1 = (const float*)d_in[30]; const float* b1 = (const float*)d_in[31];
  const float* w2 = (const float*)d_in[32]; const float* b2 = (const float*)d_in[33];

  char* wsb = (char*)d_ws;
  size_t off = 0;
  auto alloc = [&](size_t bytes) -> void* {
    void* r = wsb + off;
    off += (bytes + 255) & ~(size_t)255;
    return r;
  };
  float* em   = (float*)alloc((size_t)6 * D * 4);
  float* bckv = (float*)alloc((size_t)CKV * 4);
  float* ball = (float*)alloc((size_t)ND * 4);
  float* sx   = (float*)alloc((size_t)S * 4);
  float* sumq = (float*)alloc((size_t)S * 4);
  float* sw   = (float*)alloc((size_t)ND * 4);
  float* zp   = (float*)alloc((size_t)ND * 4);
  u16* qx     = (u16*)alloc((size_t)S * D * 2);      // union: cvtg (cross V^T, 1.6MB)
  u16* qw     = (u16*)alloc((size_t)ND * D * 2);     // union: vtg (self V^T, 7.9MB)
  float* qkv  = (float*)alloc((size_t)S * ND * 4);   // union: h3 (S*FF*2 < S*ND*4)
  u16* qkvb   = (u16*)alloc((size_t)S * ND * 2);     // bf16 q(scaled)/k roped + v
  u16* attnb  = (u16*)alloc((size_t)S * D * 2);      // union: h2
  u16* hx     = (u16*)alloc((size_t)S * D * 2);      // union: cqb
  float* cq   = (float*)alloc((size_t)S * D * 4);    // union: x2
  float* ckv  = (float*)alloc((size_t)L2C * CKV * 4);
  u16* ctxb   = (u16*)alloc((size_t)L2C * D * 2);    // union: ckvb (k section bf16)
  u16* cattn  = (u16*)alloc((size_t)S * D * 2);
  u16* wo_b   = (u16*)alloc((size_t)D * D * 2);
  u16* cwq_b  = (u16*)alloc((size_t)D * D * 2);
  u16* cwkv_b = (u16*)alloc((size_t)2 * D * D * 2);
  u16* cwo_b  = (u16*)alloc((size_t)D * D * 2);
  u16* w1_b   = (u16*)alloc((size_t)FF * D * 2);
  u16* w2_b   = (u16*)alloc((size_t)D * FF * 2);
  u16* h3 = (u16*)qkv;
  u16* h2 = attnb;
  u16* vtg = qw;        // [12][128][2560] bf16
  u16* cvtg = qx;       // [12][128][512] bf16
  u16* cqb = hx;
  u16* ckvb = ctxb;
  float* x2 = cq;
  float* x1 = (float*)d_out;
  float* outp = (float*)d_out;

  auto cvt = [&](const float* in, u16* op, size_t n) {
    int n4 = (int)(n / 4);
    int blocks = (n4 + 255) / 256; if (blocks > 4096) blocks = 4096;
    cvt_bf16_kernel<<<blocks, 256, 0, stream>>>(in, op, n4);
  };

  pack_kernel<<<36, 256, 0, stream>>>(e, modulation, cbk, cbv, em, bckv);
  cvt(wo, wo_b, (size_t)D * D);
  cvt(cwq, cwq_b, (size_t)D * D);
  cvt(cwk, cwkv_b, (size_t)D * D);
  cvt(cwv, cwkv_b + (size_t)D * D, (size_t)D * D);
  cvt(cwo, cwo_b, (size_t)D * D);
  cvt(w1, w1_b, (size_t)FF * D);
  cvt(w2, w2_b, (size_t)D * FF);
  cvt(context, ctxb, (size_t)L2C * D);

  ln_quant_kernel<<<S, 256, 0, stream>>>(x, em, qx, sx, sumq);
  quantw_kernel<<<ND, 256, 0, stream>>>(wq, wk, wv, bq, bk, bv, qw, sw, zp, ball);

  // qkv = dequant(qx @ qw^T) : [S][4608] fp32   (720 blocks @128x128)
  gemm_bt_kernel<1><<<dim3(ND / 128, S / 128), 256, 0, stream>>>(
      qx, qw, qkv, ND, D, ball, sx, sumq, sw, zp, nullptr, nullptr);

  // qkvb = bf16(rms+rope(q,k), v); q pre-scaled by 1/sqrt(128)
  rmsrope_b_kernel<<<S, 256, 0, stream>>>(qkv, qkvb, gq, gk, freqs, grid_sz);
  // vtg = V^T (self)  [12][128][2560]
  vtrans_kernel<<<dim3(S / 64, 12), 256, 0, stream>>>(qkv + 3072, ND, vtg, S);

  fattn_kernel<<<dim3(S / 64, 12), 256, 0, stream>>>(
      qkvb, ND, qkvb + 1536, ND, vtg, attnb, D, seq_lens, S);

  // x1 = x + (attn @ wo^T + bo) * gm   (480 blocks @64x128)
  gemm64_bt_kernel<2><<<dim3(D / 128, S / 64), 256, 0, stream>>>(
      attnb, wo_b, x1, D, D, bo, nullptr, nullptr, nullptr, nullptr, em + 2 * D, x);

  ln_affine_kernel<<<S, 256, 0, stream>>>(x1, hx, n3w, n3b, 0.f);

  gemm64_bt_kernel<0><<<dim3(D / 128, S / 64), 256, 0, stream>>>(
      hx, cwq_b, cq, D, D, cbq, nullptr, nullptr, nullptr, nullptr, nullptr, nullptr);
  gemm64_bt_kernel<0><<<dim3(CKV / 128, L2C / 64), 256, 0, stream>>>(
      ctxb, cwkv_b, ckv, CKV, D, bckv, nullptr, nullptr, nullptr, nullptr, nullptr, nullptr);

  // cqb = bf16(rms(cq)*cgq * 1/sqrt(128)); ckvb = bf16(rms(ck)*cgk)
  rms_bf16_kernel<<<S, 256, 0, stream>>>(cq, cqb, cgq, D, D, 0.08838834764831845f);
  rms_bf16_kernel<<<L2C, 256, 0, stream>>>(ckv, ckvb, cgk, CKV, D, 1.f);
  // cvtg = V^T (cross) [12][128][512]
  vtrans_kernel<<<dim3(L2C / 64, 12), 256, 0, stream>>>(ckv + 1536, CKV, cvtg, L2C);

  fattn_kernel<<<dim3(S / 64, 12), 256, 0, stream>>>(
      cqb, D, ckvb, D, cvtg, cattn, D, ctx_lens, L2C);

  // x2 = x1 + cattn @ cwo^T + cbo
  gemm64_bt_kernel<2><<<dim3(D / 128, S / 64), 256, 0, stream>>>(
      cattn, cwo_b, x2, D, D, cbo, nullptr, nullptr, nullptr, nullptr, nullptr, x1);

  ln_affine_kernel<<<S, 256, 0, stream>>>(x2, h2, em + 4 * D, em + 3 * D, 1.f);

  // h3 = gelu(h2 @ w1^T + b1) (bf16)   (1400 blocks @128x128)
  gemm_bt_kernel<3><<<dim3(FF / 128, S / 128), 256, 0, stream>>>(
      h2, w1_b, h3, FF, D, b1, nullptr, nullptr, nullptr, nullptr, nullptr, nullptr);

  // out = x2 + (h3 @ w2^T + b2) * gmlp   (480 blocks @64x128)
  gemm64_bt_kernel<2><<<dim3(D / 128, S / 64), 256, 0, stream>>>(
      h3, w2_b, outp, D, FF, b2, nullptr, nullptr, nullptr, nullptr, em + 5 * D, x2);
}

// Round 5
// 939.338 us; speedup vs baseline: 1.1799x; 1.0779x over previous
//
#include <hip/hip_runtime.h>
#include <stdint.h>

// WanAttentionBlock forward on gfx950 — round 5.
// gemm64: BK=64 double-buffered, 2x2 wave grid (32x64 wave tile), 8-slot XOR
// swizzle, optional split-K=2 (w2) with fused reduce+epilogue.
// Shapes: B=1, S=2560, DIM=1536, HEADS=12, HD=128, FFN=8960, L2=512.

typedef unsigned short u16;
typedef __bf16 bf16x8 __attribute__((ext_vector_type(8)));
typedef float f32x4 __attribute__((ext_vector_type(4)));

#define DEV __device__ __forceinline__

DEV u16 f2b(float f) {                    // fp32 -> bf16 RNE
  uint32_t u = __float_as_uint(f);
  u += 0x7fffu + ((u >> 16) & 1u);
  return (u16)(u >> 16);
}

DEV float gelu_tanh(float v) {
  float u = 0.7978845608028654f * (v + 0.044715f * v * v * v);
  return 0.5f * v * (1.0f + tanhf(u));
}

// async 16B global->LDS (wave-uniform LDS base + lane*16)
DEV void gl_lds16(const u16* g, u16* l) {
  __builtin_amdgcn_global_load_lds(
      (const __attribute__((address_space(1))) void*)g,
      (__attribute__((address_space(3))) void*)l, 16, 0, 0);
}

// ---- block reductions (256 threads = 4 waves) ----
DEV float bred_sum(float v, float* scr) {
  #pragma unroll
  for (int o = 32; o; o >>= 1) v += __shfl_down(v, o, 64);
  if ((threadIdx.x & 63) == 0) scr[threadIdx.x >> 6] = v;
  __syncthreads();
  v = scr[0] + scr[1] + scr[2] + scr[3];
  __syncthreads();
  return v;
}
DEV float bred_max(float v, float* scr) {
  #pragma unroll
  for (int o = 32; o; o >>= 1) v = fmaxf(v, __shfl_down(v, o, 64));
  if ((threadIdx.x & 63) == 0) scr[threadIdx.x >> 6] = v;
  __syncthreads();
  v = fmaxf(fmaxf(scr[0], scr[1]), fmaxf(scr[2], scr[3]));
  __syncthreads();
  return v;
}
DEV float bred_min(float v, float* scr) {
  #pragma unroll
  for (int o = 32; o; o >>= 1) v = fminf(v, __shfl_down(v, o, 64));
  if ((threadIdx.x & 63) == 0) scr[threadIdx.x >> 6] = v;
  __syncthreads();
  v = fminf(fminf(scr[0], scr[1]), fminf(scr[2], scr[3]));
  __syncthreads();
  return v;
}

// ---- small prep kernels ----
__global__ __launch_bounds__(256) void pack_kernel(
    const float* __restrict__ e, const float* __restrict__ mod,
    const float* __restrict__ cbk, const float* __restrict__ cbv,
    float* __restrict__ em, float* __restrict__ bckv) {
  int i = blockIdx.x * 256 + threadIdx.x;
  if (i < 9216) em[i] = e[i] + mod[i];
  if (i < 3072) bckv[i] = (i < 1536) ? cbk[i] : cbv[i - 1536];
}

__global__ __launch_bounds__(256) void cvt_bf16_kernel(
    const float* __restrict__ in, u16* __restrict__ out, int n4) {
  int stride = gridDim.x * 256;
  for (int i = blockIdx.x * 256 + threadIdx.x; i < n4; i += stride) {
    float4 v = ((const float4*)in)[i];
    uint2 r;
    r.x = (uint32_t)f2b(v.x) | ((uint32_t)f2b(v.y) << 16);
    r.y = (uint32_t)f2b(v.z) | ((uint32_t)f2b(v.w) << 16);
    ((uint2*)out)[i] = r;
  }
}

// LN + modulation + per-token dynamic int8 quant (stored as exact bf16)
__global__ __launch_bounds__(256) void ln_quant_kernel(
    const float* __restrict__ x, const float* __restrict__ em,
    u16* __restrict__ qx, float* __restrict__ sx, float* __restrict__ sumq) {
  __shared__ float scr[4];
  const int row = blockIdx.x, tid = threadIdx.x;
  const float* xr = x + (size_t)row * 1536;
  float v[6], s = 0.f, s2 = 0.f;
  #pragma unroll
  for (int t = 0; t < 6; t++) { v[t] = xr[tid + t * 256]; s += v[t]; s2 += v[t] * v[t]; }
  s = bred_sum(s, scr); s2 = bred_sum(s2, scr);
  float mean = s / 1536.f;
  float var = s2 / 1536.f - mean * mean;
  float inv = rsqrtf(var + 1e-6f);
  float hv[6], amax = 0.f;
  #pragma unroll
  for (int t = 0; t < 6; t++) {
    int i = tid + t * 256;
    hv[t] = (v[t] - mean) * inv * (1.f + em[1536 + i]) + em[i];
    amax = fmaxf(amax, fabsf(hv[t]));
  }
  amax = bred_max(amax, scr);
  float sxv = fmaxf(amax / 127.f, 1e-8f);
  float qs = 0.f;
  #pragma unroll
  for (int t = 0; t < 6; t++) {
    int i = tid + t * 256;
    float q = fminf(fmaxf(rintf(hv[t] / sxv), -127.f), 127.f);
    qs += q;
    qx[(size_t)row * 1536 + i] = f2b(q);
  }
  qs = bred_sum(qs, scr);
  if (tid == 0) { sx[row] = sxv; sumq[row] = qs; }
}

// per-output-channel asymmetric int8 weight quant for stacked [wq;wk;wv]
__global__ __launch_bounds__(256) void quantw_kernel(
    const float* __restrict__ wq, const float* __restrict__ wk, const float* __restrict__ wv,
    const float* __restrict__ bq, const float* __restrict__ bk, const float* __restrict__ bv,
    u16* __restrict__ qw, float* __restrict__ sw, float* __restrict__ zp, float* __restrict__ ball) {
  __shared__ float scr[4];
  const int row = blockIdx.x, tid = threadIdx.x;
  const int sel = (row >= 3072) ? 2 : (row >= 1536 ? 1 : 0);
  const int r = row - sel * 1536;
  const float* w = sel == 0 ? wq : (sel == 1 ? wk : wv);
  const float* bb = sel == 0 ? bq : (sel == 1 ? bk : bv);
  const float* wr = w + (size_t)r * 1536;
  float v[6], mn = 1e30f, mx = -1e30f;
  #pragma unroll
  for (int t = 0; t < 6; t++) { v[t] = wr[tid + t * 256]; mn = fminf(mn, v[t]); mx = fmaxf(mx, v[t]); }
  mn = bred_min(mn, scr); mx = bred_max(mx, scr);
  float s = fmaxf((mx - mn) / 255.f, 1e-8f);
  float z = rintf(-128.f - mn / s);
  #pragma unroll
  for (int t = 0; t < 6; t++) {
    int i = tid + t * 256;
    float q = fminf(fmaxf(rintf(v[t] / s) + z, -128.f), 127.f);
    qw[(size_t)row * 1536 + i] = f2b(q);
  }
  if (tid == 0) { sw[row] = s; zp[row] = z; ball[row] = bb[r]; }
}

// epilogue helper
template<int EP>
DEV void gemm_epilogue(float v, int row, int col, int N, void* Cout,
                       const float* bias, const float* sxp, const float* sumqp,
                       const float* swp, const float* zpp,
                       const float* gp, const float* residp) {
  size_t idx = (size_t)row * N + col;
  if constexpr (EP == 0) {
    ((float*)Cout)[idx] = v + bias[col];
  } else if constexpr (EP == 1) {
    v = (v - sumqp[row] * zpp[col]) * (sxp[row] * swp[col]) + bias[col];
    ((float*)Cout)[idx] = v;
  } else if constexpr (EP == 2) {
    v += bias[col];
    if (gp) v *= gp[col];
    ((float*)Cout)[idx] = v + residp[idx];
  } else if constexpr (EP == 3) {
    ((u16*)Cout)[idx] = f2b(gelu_tanh(v + bias[col]));
  } else {
    ((float*)Cout)[idx] = v;       // raw partial (split-K)
  }
}

// ---- MFMA GEMM (m97-style): C[M,N] = A[M,K] * B[N,K]^T ----
// 128x128 tile, BK=32, async global->LDS staging, XOR chunk swizzle.
template<int EP>
__global__ __launch_bounds__(256) void gemm_bt_kernel(
    const u16* __restrict__ A, const u16* __restrict__ B, void* __restrict__ Cout,
    int N, int K, const float* __restrict__ bias,
    const float* __restrict__ sxp, const float* __restrict__ sumqp,
    const float* __restrict__ swp, const float* __restrict__ zpp,
    const float* __restrict__ gp, const float* __restrict__ residp) {
  __shared__ __align__(16) u16 As[128 * 32];
  __shared__ __align__(16) u16 Bs[128 * 32];
  const int tid = threadIdx.x;
  const int wave = tid >> 6, lane = tid & 63;
  const int wm = wave >> 1, wn = wave & 1;
  const int quad = lane >> 4, l16 = lane & 15;
  const int m0 = blockIdx.y * 128, n0 = blockIdx.x * 128;

  int srow[2], scol[2];
  #pragma unroll
  for (int i = 0; i < 2; i++) {
    int row = (wave * 2 + i) * 16 + (lane >> 2);
    int chunk = ((lane & 3) - (row >> 1)) & 3;
    srow[i] = row; scol[i] = chunk * 8;
  }

  f32x4 acc[4][4];
  #pragma unroll
  for (int i = 0; i < 4; i++)
    #pragma unroll
    for (int j = 0; j < 4; j++) acc[i][j] = (f32x4){0.f, 0.f, 0.f, 0.f};

  for (int k0 = 0; k0 < K; k0 += 32) {
    #pragma unroll
    for (int i = 0; i < 2; i++) {
      gl_lds16(A + (size_t)(m0 + srow[i]) * K + k0 + scol[i], &As[(wave * 2 + i) * 512]);
      gl_lds16(B + (size_t)(n0 + srow[i]) * K + k0 + scol[i], &Bs[(wave * 2 + i) * 512]);
    }
    __syncthreads();
    bf16x8 af[4], bfv[4];
    #pragma unroll
    for (int mi = 0; mi < 4; mi++) {
      int row = wm * 64 + mi * 16 + l16;
      af[mi] = *(const bf16x8*)&As[row * 32 + (((quad + (row >> 1)) & 3) * 8)];
    }
    #pragma unroll
    for (int ni = 0; ni < 4; ni++) {
      int row = wn * 64 + ni * 16 + l16;
      bfv[ni] = *(const bf16x8*)&Bs[row * 32 + (((quad + (row >> 1)) & 3) * 8)];
    }
    #pragma unroll
    for (int mi = 0; mi < 4; mi++)
      #pragma unroll
      for (int ni = 0; ni < 4; ni++)
        acc[mi][ni] = __builtin_amdgcn_mfma_f32_16x16x32_bf16(af[mi], bfv[ni], acc[mi][ni], 0, 0, 0);
    __syncthreads();
  }
  #pragma unroll
  for (int mi = 0; mi < 4; mi++)
    #pragma unroll
    for (int ni = 0; ni < 4; ni++) {
      int col = n0 + wn * 64 + ni * 16 + l16;
      #pragma unroll
      for (int r = 0; r < 4; r++)
        gemm_epilogue<EP>(acc[mi][ni][r], m0 + wm * 64 + mi * 16 + quad * 4 + r, col,
                          N, Cout, bias, sxp, sumqp, swp, zpp, gp, residp);
    }
}

// ---- 64x128 BK=64 double-buffered GEMM (N=1536 outputs; optional split-K) ----
// K = row stride; KC = this chunk's K extent; blockIdx.z selects chunk.
// EP 4: raw fp32 partial -> Cout/Cout2 per z.
template<int EP>
__global__ __launch_bounds__(256) void gemm64_bt_kernel(
    const u16* __restrict__ A, const u16* __restrict__ B,
    void* __restrict__ Cout, void* __restrict__ Cout2, int N, int K, int KC,
    const float* __restrict__ bias,
    const float* __restrict__ sxp, const float* __restrict__ sumqp,
    const float* __restrict__ swp, const float* __restrict__ zpp,
    const float* __restrict__ gp, const float* __restrict__ residp) {
  __shared__ __align__(16) u16 As[2][64 * 64];
  __shared__ __align__(16) u16 Bs[2][128 * 64];
  const int tid = threadIdx.x;
  const int wave = tid >> 6, lane = tid & 63;
  const int wm = wave >> 1, wn = wave & 1;
  const int quad = lane >> 4, l16 = lane & 15;
  const int m0 = blockIdx.y * 64, n0 = blockIdx.x * 128;
  const int kstart = blockIdx.z * KC;

  // staging coords: row has 8 chunks of 16B; chunk c stored at slot (c+(row>>1))&7
  int arow[2], acol[2], brow[4], bcol[4];
  #pragma unroll
  for (int i = 0; i < 2; i++) {
    int row = (wave * 2 + i) * 8 + (lane >> 3);
    arow[i] = row; acol[i] = (((lane & 7) - (row >> 1)) & 7) * 8;
  }
  #pragma unroll
  for (int i = 0; i < 4; i++) {
    int row = (wave * 4 + i) * 8 + (lane >> 3);
    brow[i] = row; bcol[i] = (((lane & 7) - (row >> 1)) & 7) * 8;
  }

  f32x4 acc[2][4];
  #pragma unroll
  for (int i = 0; i < 2; i++)
    #pragma unroll
    for (int j = 0; j < 4; j++) acc[i][j] = (f32x4){0.f, 0.f, 0.f, 0.f};

  const int nk = KC >> 6;
  auto stage = [&](int buf, int k0) {
    #pragma unroll
    for (int i = 0; i < 2; i++)
      gl_lds16(A + (size_t)(m0 + arow[i]) * K + kstart + k0 + acol[i],
               &As[buf][(wave * 2 + i) * 512]);
    #pragma unroll
    for (int i = 0; i < 4; i++)
      gl_lds16(B + (size_t)(n0 + brow[i]) * K + kstart + k0 + bcol[i],
               &Bs[buf][(wave * 4 + i) * 512]);
  };
  stage(0, 0);
  for (int kt = 0; kt < nk; kt++) {
    __syncthreads();              // drains cur-buf loads; prev buf now reusable
    const int cur = kt & 1;
    if (kt + 1 < nk) stage(1 - cur, (kt + 1) << 6);
    #pragma unroll
    for (int s = 0; s < 2; s++) {
      bf16x8 af[2], bfv[4];
      #pragma unroll
      for (int mi = 0; mi < 2; mi++) {
        int row = wm * 32 + mi * 16 + l16;
        int slot = ((s * 4 + quad) + (row >> 1)) & 7;
        af[mi] = *(const bf16x8*)&As[cur][row * 64 + slot * 8];
      }
      #pragma unroll
      for (int ni = 0; ni < 4; ni++) {
        int row = wn * 64 + ni * 16 + l16;
        int slot = ((s * 4 + quad) + (row >> 1)) & 7;
        bfv[ni] = *(const bf16x8*)&Bs[cur][row * 64 + slot * 8];
      }
      #pragma unroll
      for (int mi = 0; mi < 2; mi++)
        #pragma unroll
        for (int ni = 0; ni < 4; ni++)
          acc[mi][ni] = __builtin_amdgcn_mfma_f32_16x16x32_bf16(af[mi], bfv[ni], acc[mi][ni], 0, 0, 0);
    }
  }
  void* Cuse = (EP == 4 && blockIdx.z) ? Cout2 : Cout;
  #pragma unroll
  for (int mi = 0; mi < 2; mi++)
    #pragma unroll
    for (int ni = 0; ni < 4; ni++) {
      int col = n0 + wn * 64 + ni * 16 + l16;
      #pragma unroll
      for (int r = 0; r < 4; r++)
        gemm_epilogue<EP>(acc[mi][ni][r], m0 + wm * 32 + mi * 16 + quad * 4 + r, col,
                          N, Cuse, bias, sxp, sumqp, swp, zpp, gp, residp);
    }
}

// split-K tail: out = (P0+P1+bias)*g + resid (fp32)
__global__ __launch_bounds__(256) void splitk_reduce_kernel(
    const float* __restrict__ P0, const float* __restrict__ P1,
    float* __restrict__ out, const float* __restrict__ bias,
    const float* __restrict__ g, const float* __restrict__ resid,
    int N, int n4) {
  int stride = gridDim.x * 256;
  for (int i = blockIdx.x * 256 + threadIdx.x; i < n4; i += stride) {
    float4 a = ((const float4*)P0)[i];
    float4 b = ((const float4*)P1)[i];
    float4 r = ((const float4*)resid)[i];
    int col = (i * 4) % N;
    float4 o;
    o.x = (a.x + b.x + bias[col]) * g[col] + r.x;
    o.y = (a.y + b.y + bias[col + 1]) * g[col + 1] + r.y;
    o.z = (a.z + b.z + bias[col + 2]) * g[col + 2] + r.z;
    o.w = (a.w + b.w + bias[col + 3]) * g[col + 3] + r.w;
    ((float4*)out)[i] = o;
  }
}

// RMS+gate+RoPE for q,k sections + plain convert for v; fp32 qkv -> bf16 qkvb.
__global__ __launch_bounds__(256) void rmsrope_b_kernel(
    const float* __restrict__ qkv, u16* __restrict__ qkvb,
    const float* __restrict__ gq, const float* __restrict__ gk,
    const float* __restrict__ freqs, const int* __restrict__ gsz) {
  __shared__ float scr[4];
  const int row = blockIdx.x, tid = threadIdx.x;
  const float* base = qkv + (size_t)row * 4608;
  u16* ob = qkvb + (size_t)row * 4608;
  const int gh = gsz[1], gw = gsz[2];
  const int hw = gh * gw;
  const int fi = row / hw, rem = row - fi * hw;
  const int hi = rem / gw, wi = rem - hi * gw;
  #pragma unroll
  for (int part = 0; part < 2; part++) {
    const float* p = base + part * 1536;
    u16* o = ob + part * 1536;
    const float* g = part ? gk : gq;
    const float sc = part ? 1.f : 0.08838834764831845f;
    float v[6], s2 = 0.f;
    #pragma unroll
    for (int t = 0; t < 6; t++) { v[t] = p[tid + t * 256]; s2 += v[t] * v[t]; }
    s2 = bred_sum(s2, scr);
    float inv = rsqrtf(s2 / 1536.f + 1e-6f);
    #pragma unroll
    for (int t = 0; t < 3; t++) {
      int pr = tid + t * 256;
      int c = pr & 63;
      int frow = (c < 22) ? fi : (c < 43 ? hi : wi);
      const float* fr = freqs + ((size_t)frow * 64 + c) * 2;
      float cv = fr[0], sv = fr[1];
      float x0 = p[2 * pr] * inv * g[2 * pr];
      float x1 = p[2 * pr + 1] * inv * g[2 * pr + 1];
      o[2 * pr] = f2b((x0 * cv - x1 * sv) * sc);
      o[2 * pr + 1] = f2b((x0 * sv + x1 * cv) * sc);
    }
  }
  #pragma unroll
  for (int t = 0; t < 6; t++) {
    int i = tid + t * 256;
    ob[3072 + i] = f2b(base[3072 + i]);
  }
}

// RMS (optional) + scale, fp32 -> bf16
__global__ __launch_bounds__(256) void rms_bf16_kernel(
    const float* __restrict__ X, u16* __restrict__ O, const float* __restrict__ g,
    int ldi, int ldo, float scale) {
  __shared__ float scr[4];
  const int row = blockIdx.x, tid = threadIdx.x;
  const float* xr = X + (size_t)row * ldi;
  u16* orow = O + (size_t)row * ldo;
  float v[6], s2 = 0.f;
  #pragma unroll
  for (int t = 0; t < 6; t++) { v[t] = xr[tid + t * 256]; s2 += v[t] * v[t]; }
  s2 = bred_sum(s2, scr);
  float inv = rsqrtf(s2 / 1536.f + 1e-6f) * scale;
  #pragma unroll
  for (int t = 0; t < 6; t++) {
    int i = tid + t * 256;
    orow[i] = f2b(v[t] * inv * g[i]);
  }
}

// V transpose: fp32 V[kv][ld] (per-head 128 cols) -> bf16 Vt[head][hd][Skv]
__global__ __launch_bounds__(256) void vtrans_kernel(
    const float* __restrict__ V, int ld, u16* __restrict__ Vt, int Skv) {
  __shared__ u16 T[64 * 136];
  const int h = blockIdx.y, k0 = blockIdx.x * 64, tid = threadIdx.x;
  #pragma unroll
  for (int i = 0; i < 8; i++) {
    int f4 = i * 256 + tid;
    int row = f4 >> 5, c4 = f4 & 31;
    float4 v = *(const float4*)(V + (size_t)(k0 + row) * ld + h * 128 + c4 * 4);
    ushort4 b;
    b.x = f2b(v.x); b.y = f2b(v.y); b.z = f2b(v.z); b.w = f2b(v.w);
    *(ushort4*)&T[row * 136 + c4 * 4] = b;
  }
  __syncthreads();
  #pragma unroll
  for (int i = 0; i < 4; i++) {
    int f8 = i * 256 + tid;
    int hd = f8 >> 3, kc = f8 & 7;
    u16 tmp[8];
    #pragma unroll
    for (int j = 0; j < 8; j++) tmp[j] = T[(kc * 8 + j) * 136 + hd];
    *(uint4*)(Vt + ((size_t)h * 128 + hd) * Skv + k0 + kc * 8) = *(const uint4*)tmp;
  }
}

// ---- MFMA flash attention ----
__global__ __launch_bounds__(256) void fattn_kernel(
    const u16* __restrict__ Q, int ldq, const u16* __restrict__ Kg, int ldk,
    const u16* __restrict__ Vtg, u16* __restrict__ O, int ldo,
    const int* __restrict__ klen_ptr, int kmax) {
  __shared__ __align__(16) u16 Qs[64 * 136];
  __shared__ __align__(16) u16 Ks[64 * 136];
  __shared__ __align__(16) u16 Vt[128 * 72];
  __shared__ __align__(16) u16 Pt[4][16 * 72];
  const int tid = threadIdx.x, wave = tid >> 6, lane = tid & 63;
  const int quad = lane >> 4, l16 = lane & 15;
  const int h = blockIdx.y;
  const int q0 = blockIdx.x * 64;
  int klen = klen_ptr[0]; if (klen > kmax) klen = kmax;
  const u16* vbase = Vtg + (size_t)h * 128 * kmax;

  #pragma unroll
  for (int i = 0; i < 4; i++) {
    int c8 = i * 256 + tid;
    int row = c8 >> 4, cc = (c8 & 15) * 8;
    *(uint4*)&Qs[row * 136 + cc] = *(const uint4*)(Q + (size_t)(q0 + row) * ldq + h * 128 + cc);
  }
  __syncthreads();
  bf16x8 qf[4];
  #pragma unroll
  for (int s = 0; s < 4; s++)
    qf[s] = *(const bf16x8*)&Qs[(wave * 16 + l16) * 136 + s * 32 + quad * 8];

  float m_r[4] = {-1e30f, -1e30f, -1e30f, -1e30f};
  float l_r[4] = {0.f, 0.f, 0.f, 0.f};
  f32x4 oacc[8];
  #pragma unroll
  for (int n8 = 0; n8 < 8; n8++) oacc[n8] = (f32x4){0.f, 0.f, 0.f, 0.f};

  const int ktiles = (klen + 63) >> 6;
  for (int kt = 0; kt < ktiles; kt++) {
    const int k0 = kt * 64;
    __syncthreads();
    #pragma unroll
    for (int i = 0; i < 4; i++) {
      int c8 = i * 256 + tid;
      int row = c8 >> 4, cc = (c8 & 15) * 8;
      *(uint4*)&Ks[row * 136 + cc] = *(const uint4*)(Kg + (size_t)(k0 + row) * ldk + h * 128 + cc);
    }
    #pragma unroll
    for (int i = 0; i < 4; i++) {
      int f8 = i * 256 + tid;
      int hd = f8 >> 3, kc = f8 & 7;
      *(uint4*)&Vt[hd * 72 + kc * 8] = *(const uint4*)(vbase + (size_t)hd * kmax + k0 + kc * 8);
    }
    __syncthreads();
    f32x4 sacc[4];
    #pragma unroll
    for (int ni = 0; ni < 4; ni++) sacc[ni] = (f32x4){0.f, 0.f, 0.f, 0.f};
    #pragma unroll
    for (int ni = 0; ni < 4; ni++)
      #pragma unroll
      for (int s = 0; s < 4; s++) {
        bf16x8 kf = *(const bf16x8*)&Ks[(ni * 16 + l16) * 136 + s * 32 + quad * 8];
        sacc[ni] = __builtin_amdgcn_mfma_f32_16x16x32_bf16(qf[s], kf, sacc[ni], 0, 0, 0);
      }
    float alpha_r[4];
    #pragma unroll
    for (int r = 0; r < 4; r++) {
      float mx = -1e30f;
      #pragma unroll
      for (int ni = 0; ni < 4; ni++) {
        int col = k0 + ni * 16 + l16;
        float sv = (col < klen) ? sacc[ni][r] : -1e30f;
        sacc[ni][r] = sv;
        mx = fmaxf(mx, sv);
      }
      #pragma unroll
      for (int off = 1; off < 16; off <<= 1) mx = fmaxf(mx, __shfl_xor(mx, off, 64));
      float mnew = fmaxf(m_r[r], mx);
      float alpha = __expf(m_r[r] - mnew);
      float rsum = 0.f;
      float pv[4];
      #pragma unroll
      for (int ni = 0; ni < 4; ni++) {
        float p = __expf(sacc[ni][r] - mnew);
        pv[ni] = p;
        rsum += p;
      }
      #pragma unroll
      for (int off = 1; off < 16; off <<= 1) rsum += __shfl_xor(rsum, off, 64);
      l_r[r] = l_r[r] * alpha + rsum;
      m_r[r] = mnew;
      alpha_r[r] = alpha;
      #pragma unroll
      for (int ni = 0; ni < 4; ni++)
        Pt[wave][(quad * 4 + r) * 72 + ni * 16 + l16] = f2b(pv[ni]);
    }
    #pragma unroll
    for (int n8 = 0; n8 < 8; n8++)
      #pragma unroll
      for (int r = 0; r < 4; r++) oacc[n8][r] *= alpha_r[r];
    #pragma unroll
    for (int s2 = 0; s2 < 2; s2++) {
      bf16x8 pf = *(const bf16x8*)&Pt[wave][l16 * 72 + s2 * 32 + quad * 8];
      #pragma unroll
      for (int n8 = 0; n8 < 8; n8++) {
        bf16x8 vf = *(const bf16x8*)&Vt[(n8 * 16 + l16) * 72 + s2 * 32 + quad * 8];
        oacc[n8] = __builtin_amdgcn_mfma_f32_16x16x32_bf16(pf, vf, oacc[n8], 0, 0, 0);
      }
    }
  }
  float rl[4];
  #pragma unroll
  for (int r = 0; r < 4; r++) rl[r] = 1.f / l_r[r];
  #pragma unroll
  for (int n8 = 0; n8 < 8; n8++)
    #pragma unroll
    for (int r = 0; r < 4; r++) {
      int row = q0 + wave * 16 + quad * 4 + r;
      O[(size_t)row * ldo + h * 128 + n8 * 16 + l16] = f2b(oacc[n8][r] * rl[r]);
    }
}

// out_bf16 = LN(x) * (addone + w) + b
__global__ __launch_bounds__(256) void ln_affine_kernel(
    const float* __restrict__ X, u16* __restrict__ O,
    const float* __restrict__ w, const float* __restrict__ b, float addone) {
  __shared__ float scr[4];
  const int row = blockIdx.x, tid = threadIdx.x;
  const float* xr = X + (size_t)row * 1536;
  float v[6], s = 0.f, s2 = 0.f;
  #pragma unroll
  for (int t = 0; t < 6; t++) { v[t] = xr[tid + t * 256]; s += v[t]; s2 += v[t] * v[t]; }
  s = bred_sum(s, scr); s2 = bred_sum(s2, scr);
  float mean = s / 1536.f;
  float inv = rsqrtf(s2 / 1536.f - mean * mean + 1e-6f);
  #pragma unroll
  for (int t = 0; t < 6; t++) {
    int i = tid + t * 256;
    O[(size_t)row * 1536 + i] = f2b((v[t] - mean) * inv * (addone + w[i]) + b[i]);
  }
}

extern "C" void kernel_launch(void* const* d_in, const int* in_sizes, int n_in,
                              void* d_out, int out_size, void* d_ws, size_t ws_size,
                              hipStream_t stream) {
  (void)in_sizes; (void)n_in; (void)out_size; (void)ws_size;
  const int S = 2560, D = 1536, L2C = 512, FF = 8960, ND = 4608, CKV = 3072;

  const float* x = (const float*)d_in[0];
  const float* e = (const float*)d_in[1];
  const int* seq_lens = (const int*)d_in[2];
  const int* grid_sz = (const int*)d_in[3];
  const float* freqs = (const float*)d_in[4];
  const float* context = (const float*)d_in[5];
  const int* ctx_lens = (const int*)d_in[6];
  const float* modulation = (const float*)d_in[7];
  const float* wq = (const float*)d_in[8];  const float* bq = (const float*)d_in[9];
  const float* wk = (const float*)d_in[10]; const float* bk = (const float*)d_in[11];
  const float* wv = (const float*)d_in[12]; const float* bv = (const float*)d_in[13];
  const float* wo = (const float*)d_in[14]; const float* bo = (const float*)d_in[15];
  const float* gq = (const float*)d_in[16]; const float* gk = (const float*)d_in[17];
  const float* n3w = (const float*)d_in[18]; const float* n3b = (const float*)d_in[19];
  const float* cwq = (const float*)d_in[20]; const float* cbq = (const float*)d_in[21];
  const float* cwk = (const float*)d_in[22]; const float* cbk = (const float*)d_in[23];
  const float* cwv = (const float*)d_in[24]; const float* cbv = (const float*)d_in[25];
  const float* cwo = (const float*)d_in[26]; const float* cbo = (const float*)d_in[27];
  const float* cgq = (const float*)d_in[28]; const float* cgk = (const float*)d_in[29];
  const float* w1 = (const float*)d_in[30]; const float* b1 = (const float*)d_in[31];
  const float* w2 = (const float*)d_in[32]; const float* b2 = (const float*)d_in[33];

  char* wsb = (char*)d_ws;
  size_t off = 0;
  auto alloc = [&](size_t bytes) -> void* {
    void* r = wsb + off;
    off += (bytes + 255) & ~(size_t)255;
    return r;
  };
  float* em   = (float*)alloc((size_t)6 * D * 4);
  float* bckv = (float*)alloc((size_t)CKV * 4);
  float* ball = (float*)alloc((size_t)ND * 4);
  float* sx   = (float*)alloc((size_t)S * 4);
  float* sumq = (float*)alloc((size_t)S * 4);
  float* sw   = (float*)alloc((size_t)ND * 4);
  float* zp   = (float*)alloc((size_t)ND * 4);
  u16* qx     = (u16*)alloc((size_t)S * D * 2);      // union: cvtg; P0 head
  u16* qw     = (u16*)alloc((size_t)ND * D * 2);     // union: vtg; P0 tail (qx+qw = 22.1MB >= 15.7MB)
  float* qkv  = (float*)alloc((size_t)S * ND * 4);   // union: h3
  u16* qkvb   = (u16*)alloc((size_t)S * ND * 2);     // union: P1 (23.6MB >= 15.7MB)
  u16* attnb  = (u16*)alloc((size_t)S * D * 2);      // union: h2
  u16* hx     = (u16*)alloc((size_t)S * D * 2);      // union: cqb
  float* cq   = (float*)alloc((size_t)S * D * 4);    // union: x2
  float* ckv  = (float*)alloc((size_t)L2C * CKV * 4);
  u16* ctxb   = (u16*)alloc((size_t)L2C * D * 2);    // union: ckvb
  u16* cattn  = (u16*)alloc((size_t)S * D * 2);
  u16* wo_b   = (u16*)alloc((size_t)D * D * 2);
  u16* cwq_b  = (u16*)alloc((size_t)D * D * 2);
  u16* cwkv_b = (u16*)alloc((size_t)2 * D * D * 2);
  u16* cwo_b  = (u16*)alloc((size_t)D * D * 2);
  u16* w1_b   = (u16*)alloc((size_t)FF * D * 2);
  u16* w2_b   = (u16*)alloc((size_t)D * FF * 2);
  u16* h3 = (u16*)qkv;
  u16* h2 = attnb;
  u16* vtg = qw;        // [12][128][2560] bf16
  u16* cvtg = qx;       // [12][128][512] bf16
  u16* cqb = hx;
  u16* ckvb = ctxb;
  float* x2 = cq;
  float* x1 = (float*)d_out;
  float* outp = (float*)d_out;
  float* P0 = (float*)qx;     // 15.7MB in qx+qw region (dead during FFN)
  float* P1 = (float*)qkvb;   // 15.7MB in qkvb region (dead during FFN)

  auto cvt = [&](const float* in, u16* op, size_t n) {
    int n4 = (int)(n / 4);
    int blocks = (n4 + 255) / 256; if (blocks > 4096) blocks = 4096;
    cvt_bf16_kernel<<<blocks, 256, 0, stream>>>(in, op, n4);
  };

  pack_kernel<<<36, 256, 0, stream>>>(e, modulation, cbk, cbv, em, bckv);
  cvt(wo, wo_b, (size_t)D * D);
  cvt(cwq, cwq_b, (size_t)D * D);
  cvt(cwk, cwkv_b, (size_t)D * D);
  cvt(cwv, cwkv_b + (size_t)D * D, (size_t)D * D);
  cvt(cwo, cwo_b, (size_t)D * D);
  cvt(w1, w1_b, (size_t)FF * D);
  cvt(w2, w2_b, (size_t)D * FF);
  cvt(context, ctxb, (size_t)L2C * D);

  ln_quant_kernel<<<S, 256, 0, stream>>>(x, em, qx, sx, sumq);
  quantw_kernel<<<ND, 256, 0, stream>>>(wq, wk, wv, bq, bk, bv, qw, sw, zp, ball);

  // qkv = dequant(qx @ qw^T) : [S][4608] fp32   (720 blocks @128x128)
  gemm_bt_kernel<1><<<dim3(ND / 128, S / 128), 256, 0, stream>>>(
      qx, qw, qkv, ND, D, ball, sx, sumq, sw, zp, nullptr, nullptr);

  rmsrope_b_kernel<<<S, 256, 0, stream>>>(qkv, qkvb, gq, gk, freqs, grid_sz);
  vtrans_kernel<<<dim3(S / 64, 12), 256, 0, stream>>>(qkv + 3072, ND, vtg, S);

  fattn_kernel<<<dim3(S / 64, 12), 256, 0, stream>>>(
      qkvb, ND, qkvb + 1536, ND, vtg, attnb, D, seq_lens, S);

  // x1 = x + (attn @ wo^T + bo) * gm
  gemm64_bt_kernel<2><<<dim3(D / 128, S / 64), 256, 0, stream>>>(
      attnb, wo_b, x1, nullptr, D, D, D, bo, nullptr, nullptr, nullptr, nullptr, em + 2 * D, x);

  ln_affine_kernel<<<S, 256, 0, stream>>>(x1, hx, n3w, n3b, 0.f);

  gemm64_bt_kernel<0><<<dim3(D / 128, S / 64), 256, 0, stream>>>(
      hx, cwq_b, cq, nullptr, D, D, D, cbq, nullptr, nullptr, nullptr, nullptr, nullptr, nullptr);
  gemm64_bt_kernel<0><<<dim3(CKV / 128, L2C / 64), 256, 0, stream>>>(
      ctxb, cwkv_b, ckv, nullptr, CKV, D, D, bckv, nullptr, nullptr, nullptr, nullptr, nullptr, nullptr);

  rms_bf16_kernel<<<S, 256, 0, stream>>>(cq, cqb, cgq, D, D, 0.08838834764831845f);
  rms_bf16_kernel<<<L2C, 256, 0, stream>>>(ckv, ckvb, cgk, CKV, D, 1.f);
  vtrans_kernel<<<dim3(L2C / 64, 12), 256, 0, stream>>>(ckv + 1536, CKV, cvtg, L2C);

  fattn_kernel<<<dim3(S / 64, 12), 256, 0, stream>>>(
      cqb, D, ckvb, D, cvtg, cattn, D, ctx_lens, L2C);

  // x2 = x1 + cattn @ cwo^T + cbo
  gemm64_bt_kernel<2><<<dim3(D / 128, S / 64), 256, 0, stream>>>(
      cattn, cwo_b, x2, nullptr, D, D, D, cbo, nullptr, nullptr, nullptr, nullptr, nullptr, x1);

  ln_affine_kernel<<<S, 256, 0, stream>>>(x2, h2, em + 4 * D, em + 3 * D, 1.f);

  // h3 = gelu(h2 @ w1^T + b1) (bf16)   (1400 blocks @128x128)
  gemm_bt_kernel<3><<<dim3(FF / 128, S / 128), 256, 0, stream>>>(
      h2, w1_b, h3, FF, D, b1, nullptr, nullptr, nullptr, nullptr, nullptr, nullptr);

  // w2 split-K=2: partials P0/P1, then fused reduce+epilogue
  gemm64_bt_kernel<4><<<dim3(D / 128, S / 64, 2), 256, 0, stream>>>(
      h3, w2_b, P0, P1, D, FF, FF / 2, nullptr, nullptr, nullptr, nullptr, nullptr, nullptr, nullptr);
  splitk_reduce_kernel<<<960, 256, 0, stream>>>(
      P0, P1, outp, b2, em + 5 * D, x2, D, S * D / 4);
}